// Round 10
// baseline (1123.689 us; speedup 1.0000x reference)
//
#include <hip/hip_runtime.h>
#include <math.h>

#define NN 50000
#define DD 128
#define HH 128
#define L1 64
#define L2 32
#define OO 10

// packed B-fragment table sizes (ct * ks * 64 lanes * 8 elems)
#define NW0 16384   // W : 8 ct * 4 ks * 64 * 8
#define NW1 8192    // W1: 4 ct * 4 ks * 64 * 8
#define NW2 2048    // W2: 2 ct * 2 ks * 64 * 8
#define NWT (NW0 + NW1 + NW2)
#define MAXGRID 2048

typedef short v8s __attribute__((ext_vector_type(8)));   // 8 bf16 (4 VGPRs)
typedef float v4f __attribute__((ext_vector_type(4)));   // MFMA accumulator

// ---- bf16 helpers (manual: RNE pack) ----
__device__ __forceinline__ float bf2f_lo(unsigned u) { return __uint_as_float(u << 16); }
__device__ __forceinline__ float bf2f_hi(unsigned u) { return __uint_as_float(u & 0xffff0000u); }
__device__ __forceinline__ unsigned short f2bf(float f) {
    unsigned u = __float_as_uint(f);
    return (unsigned short)((u + 0x7fffu + ((u >> 16) & 1u)) >> 16);
}
__device__ __forceinline__ unsigned pack2(float lo, float hi) {
    return (unsigned)f2bf(lo) | ((unsigned)f2bf(hi) << 16);
}
__device__ __forceinline__ float gelu_f(float v) {
    return 0.5f * v * (1.f + erff(v * 0.70710678118654752f));
}

// ---- sharded grid barrier (monotonic counters; grid must be co-resident) ----
// 32 padded arrival counters -> master -> generation flag. ACQ_REL agent scope
// so each RMW link carries release/acquire; spinners do acquire loads.
__device__ __forceinline__ void gridbar(int g, int nb, int* barc, int* barm, int* barg)
{
    __syncthreads();
    if (threadIdx.x == 0) {
        __threadfence();
        const int per = nb >> 5;
        int a = __hip_atomic_fetch_add(&barc[(blockIdx.x & 31) << 4], 1,
                                       __ATOMIC_ACQ_REL, __HIP_MEMORY_SCOPE_AGENT);
        if (a == (g + 1) * per - 1) {
            int m = __hip_atomic_fetch_add(barm, 1, __ATOMIC_ACQ_REL, __HIP_MEMORY_SCOPE_AGENT);
            if (m == (g + 1) * 32 - 1)
                __hip_atomic_fetch_add(barg, 1, __ATOMIC_ACQ_REL, __HIP_MEMORY_SCOPE_AGENT);
        }
        while (__hip_atomic_load(barg, __ATOMIC_ACQUIRE, __HIP_MEMORY_SCOPE_AGENT) <= g)
            __builtin_amdgcn_s_sleep(2);
    }
    __syncthreads();
}

// ============ MEGA KERNEL: entire pipeline, 1 launch, 5 grid barriers ========
__global__ __launch_bounds__(256, 8) void k_mega(
    const float* __restrict__ x, const int* __restrict__ ei,
    const float* __restrict__ W, const float* __restrict__ W1,
    const float* __restrict__ W2, const float* __restrict__ W3,
    const float* __restrict__ b0v, const float* __restrict__ b1v,
    const float* __restrict__ b2v, const float* __restrict__ b3v,
    float* __restrict__ out,
    unsigned short* __restrict__ xb, unsigned* __restrict__ zrow,
    int* __restrict__ ss, int* __restrict__ counts, int* __restrict__ cursor,
    int* __restrict__ offsets, int* __restrict__ blksum, int* __restrict__ blkoff,
    int* __restrict__ wtotb, float* __restrict__ partials, float* __restrict__ accum,
    int* __restrict__ dcnt, int* __restrict__ barc, int* __restrict__ barm,
    int* __restrict__ barg,
    unsigned short* __restrict__ wtp, unsigned short* __restrict__ w1tp,
    unsigned short* __restrict__ w2tp, int E, int SSN, int NT)
{
    __shared__ __align__(16) unsigned char upool[32 * 136 * 2]; // xa/hsb/h2p
    __shared__ __align__(16) unsigned short h1b[32 * 72];
    __shared__ float b0s[DD], b1s[L1], b2s[L2];
    __shared__ float oacc[64];
    __shared__ int ssum[4], soff[4];
    __shared__ float lsum[4][64];
    __shared__ int lastf;
    unsigned short* xa  = (unsigned short*)upool;
    unsigned short* hsb = (unsigned short*)upool;
    float* h2p = (float*)upool;

    const int tid = threadIdx.x;
    const int bid = blockIdx.x;
    const int nb  = gridDim.x;
    const int gid = bid * 256 + tid;
    const int stride = nb * 256;
    const int lane = tid & 63;
    const int wv = tid >> 6;      // wave 0..3

    // ================= Phase A: prep (weights, zrow, ss fill, xcvt, hist) ====
    for (int i = gid; i < NWT; i += stride) {
        if (i < NW0) {
            const int e = i & 7, ln = (i >> 3) & 63, ks = (i >> 9) & 3, ct = i >> 11;
            wtp[i] = f2bf(W[(ks * 32 + (ln >> 4) * 8 + e) * HH + ct * 16 + (ln & 15)]);
        } else if (i < NW0 + NW1) {
            const int j = i - NW0;
            const int e = j & 7, ln = (j >> 3) & 63, ks = (j >> 9) & 3, ct = j >> 11;
            w1tp[j] = f2bf(W1[(ks * 32 + (ln >> 4) * 8 + e) * L1 + ct * 16 + (ln & 15)]);
        } else {
            const int j = i - NW0 - NW1;
            const int e = j & 7, ln = (j >> 3) & 63, ks = (j >> 9) & 1, ct = j >> 10;
            w2tp[j] = f2bf(W2[(ks * 32 + (ln >> 4) * 8 + e) * L2 + ct * 16 + (ln & 15)]);
        }
    }
    if (gid < 128) zrow[gid] = 0u;
    for (int i = gid; i < SSN; i += stride) ss[i] = NN;   // pad fill
    {
        const int HALF = NN * 32;
        for (int idx = gid; idx < 2 * HALF; idx += stride) {
            const int b = (idx >= HALF) ? 1 : 0;
            const int j = idx - b * HALF;
            const int n = j >> 5;
            const int c4 = j & 31;
            const float4 v = *(const float4*)(x + ((size_t)b * NN + n) * DD + c4 * 4);
            ushort4 o;
            o.x = f2bf(v.x); o.y = f2bf(v.y); o.z = f2bf(v.z); o.w = f2bf(v.w);
            *(ushort4*)(xb + ((size_t)n * 2 + b) * DD + c4 * 4) = o;
        }
    }
    for (int e = gid; e < E; e += stride)
        atomicAdd(&counts[ei[(size_t)E + e]], 1);   // counts zeroed by memset

    gridbar(0, nb, barc, barm, barg);

    // ================= Phase B1: per-chunk scan (chunk = 256, 196 chunks) ====
    if (bid < (NN + 255) / 256) {
        const int i = bid * 256 + tid;
        int v = (i < NN) ? ((counts[i] + 7) & ~7) : 0;
        int xx = v;
        #pragma unroll
        for (int d = 1; d < 64; d <<= 1) { int t = __shfl_up(xx, d); if (lane >= d) xx += t; }
        if (lane == 63) ssum[wv] = xx;
        __syncthreads();
        if (tid == 0) { int s = 0; for (int k = 0; k < 4; ++k) { soff[k] = s; s += ssum[k]; } }
        __syncthreads();
        const int excl = soff[wv] + xx - v;
        if (i < NN) offsets[i] = excl;
        if (tid == 255) blksum[bid] = excl + v;
    }
    gridbar(1, nb, barc, barm, barg);

    // ================= Phase B2: scan of 196 chunk sums (block 0) ============
    if (bid == 0) {
        const int nch = (NN + 255) / 256;
        int v = (tid < nch) ? blksum[tid] : 0;
        int xx = v;
        #pragma unroll
        for (int d = 1; d < 64; d <<= 1) { int t = __shfl_up(xx, d); if (lane >= d) xx += t; }
        if (lane == 63) ssum[wv] = xx;
        __syncthreads();
        if (tid == 0) { int s = 0; for (int k = 0; k < 4; ++k) { soff[k] = s; s += ssum[k]; } }
        __syncthreads();
        const int excl = soff[wv] + xx - v;
        if (tid < nch) blkoff[tid] = excl;
        if (tid == 255) wtotb[0] = excl + v;    // grand total (v=0 here)
    }
    gridbar(2, nb, barc, barm, barg);

    // ================= Phase C: bucket (CSR build) ===========================
    for (int e = gid; e < E; e += stride) {
        const int d = ei[(size_t)E + e];
        const int pos = offsets[d] + blkoff[d >> 8] + atomicAdd(&cursor[d], 1);
        ss[pos] = ei[e];
    }
    gridbar(3, nb, barc, barm, barg);

    // ================= Phase D: gather-agg + W-GEMM + gelu + MLP + colsums ===
    if (tid < DD) b0s[tid] = b0v[tid];
    if (tid < L1) b1s[tid] = b1v[tid];
    if (tid < L2) b2s[tid] = b2v[tid];
    float racc = 0.f;
    const int wtot = wtotb[0];

    for (int tile = bid; tile < NT; tile += nb) {
        const int row0 = tile * 32;
        if (tid < 64) oacc[tid] = 0.f;

        // gather-aggregate (8-padded branch-free, idx prefetch)
        {
            const int half4 = (lane >> 5) * 4;
            const int co = (lane & 31) * 8;
            #pragma unroll
            for (int j = 0; j < 4; ++j) {
                const int ln = wv * 4 + j;
                const int d = tile * 16 + ln;
                int s0 = 0, s1 = 0;
                if (d < NN) {
                    s0 = offsets[d] + blkoff[d >> 8];
                    s1 = (d + 1 < NN) ? offsets[d + 1] + blkoff[(d + 1) >> 8] : wtot;
                }
                float a[8];
                #pragma unroll
                for (int t = 0; t < 8; ++t) a[t] = 0.f;
                uint4 nidx;
                if (s0 < s1) nidx = *(const uint4*)(ss + s0 + half4);
                for (int i = s0; i < s1; ) {
                    const uint4 idx = nidx;
                    const int inext = i + 8;
                    if (inext < s1) nidx = *(const uint4*)(ss + inext + half4);
                    const uint4 r0 = *(const uint4*)(xb + (size_t)idx.x * 256 + co);
                    const uint4 r1 = *(const uint4*)(xb + (size_t)idx.y * 256 + co);
                    const uint4 r2 = *(const uint4*)(xb + (size_t)idx.z * 256 + co);
                    const uint4 r3 = *(const uint4*)(xb + (size_t)idx.w * 256 + co);
                    a[0] += bf2f_lo(r0.x); a[1] += bf2f_hi(r0.x);
                    a[2] += bf2f_lo(r0.y); a[3] += bf2f_hi(r0.y);
                    a[4] += bf2f_lo(r0.z); a[5] += bf2f_hi(r0.z);
                    a[6] += bf2f_lo(r0.w); a[7] += bf2f_hi(r0.w);
                    a[0] += bf2f_lo(r1.x); a[1] += bf2f_hi(r1.x);
                    a[2] += bf2f_lo(r1.y); a[3] += bf2f_hi(r1.y);
                    a[4] += bf2f_lo(r1.z); a[5] += bf2f_hi(r1.z);
                    a[6] += bf2f_lo(r1.w); a[7] += bf2f_hi(r1.w);
                    a[0] += bf2f_lo(r2.x); a[1] += bf2f_hi(r2.x);
                    a[2] += bf2f_lo(r2.y); a[3] += bf2f_hi(r2.y);
                    a[4] += bf2f_lo(r2.z); a[5] += bf2f_hi(r2.z);
                    a[6] += bf2f_lo(r2.w); a[7] += bf2f_hi(r2.w);
                    a[0] += bf2f_lo(r3.x); a[1] += bf2f_hi(r3.x);
                    a[2] += bf2f_lo(r3.y); a[3] += bf2f_hi(r3.y);
                    a[4] += bf2f_lo(r3.z); a[5] += bf2f_hi(r3.z);
                    a[6] += bf2f_lo(r3.w); a[7] += bf2f_hi(r3.w);
                    i = inext;
                }
                #pragma unroll
                for (int t = 0; t < 8; ++t) a[t] += __shfl_xor(a[t], 32);
                if (lane < 32) {
                    const int tr = ln * 2 + (lane >> 4);
                    const int col = (lane & 15) * 8;
                    uint4 o;
                    o.x = pack2(a[0], a[1]); o.y = pack2(a[2], a[3]);
                    o.z = pack2(a[4], a[5]); o.w = pack2(a[6], a[7]);
                    *(uint4*)(&xa[tr * 136 + col]) = o;
                }
            }
        }
        __syncthreads();

        const int lm = lane & 15;
        const int q = lane >> 4;
        const int r1 = (wv & 1) * 16;
        const int ch = wv >> 1;

        // W-GEMM (32x128 @ 128x128)
        {
            v4f acc[4];
            #pragma unroll
            for (int i = 0; i < 4; ++i) acc[i] = (v4f)(0.f);
            #pragma unroll
            for (int ks = 0; ks < 4; ++ks) {
                const int k0 = ks * 32 + q * 8;
                const v8s af = *(const v8s*)(&xa[(r1 + lm) * 136 + k0]);
                #pragma unroll
                for (int ct = 0; ct < 4; ++ct) {
                    const int ctg = ch * 4 + ct;
                    const v8s bf = *(const v8s*)(wtp + ((size_t)(ctg * 4 + ks) * 64 + lane) * 8);
                    acc[ct] = __builtin_amdgcn_mfma_f32_16x16x32_bf16(af, bf, acc[ct], 0, 0, 0);
                }
            }
            __syncthreads();
            #pragma unroll
            for (int ct = 0; ct < 4; ++ct) {
                const int col = ch * 64 + ct * 16 + lm;
                const float bias = b0s[col];
                #pragma unroll
                for (int r = 0; r < 4; ++r)
                    hsb[(r1 + q * 4 + r) * 136 + col] = f2bf(gelu_f(acc[ct][r] + bias));
            }
        }
        __syncthreads();

        // layer1 (32x128 @ 128x64)
        {
            v4f a1[2];
            a1[0] = (v4f)(0.f); a1[1] = (v4f)(0.f);
            #pragma unroll
            for (int ks = 0; ks < 4; ++ks) {
                const int k0 = ks * 32 + q * 8;
                const v8s af = *(const v8s*)(&hsb[(r1 + lm) * 136 + k0]);
                #pragma unroll
                for (int ct = 0; ct < 2; ++ct) {
                    const int ctg = ch * 2 + ct;
                    const v8s bf = *(const v8s*)(w1tp + ((size_t)(ctg * 4 + ks) * 64 + lane) * 8);
                    a1[ct] = __builtin_amdgcn_mfma_f32_16x16x32_bf16(af, bf, a1[ct], 0, 0, 0);
                }
            }
            #pragma unroll
            for (int ct = 0; ct < 2; ++ct) {
                const int col = ch * 32 + ct * 16 + lm;
                const float bias = b1s[col];
                #pragma unroll
                for (int r = 0; r < 4; ++r)
                    h1b[(r1 + q * 4 + r) * 72 + col] = f2bf(fmaxf(a1[ct][r] + bias, 0.f));
            }
        }
        __syncthreads();

        // layer2 (32x64 @ 64x32)
        {
            v4f a2 = (v4f)(0.f);
            #pragma unroll
            for (int ks = 0; ks < 2; ++ks) {
                const int k0 = ks * 32 + q * 8;
                const v8s af = *(const v8s*)(&h1b[(r1 + lm) * 72 + k0]);
                const v8s bf = *(const v8s*)(w2tp + ((size_t)(ch * 2 + ks) * 64 + lane) * 8);
                a2 = __builtin_amdgcn_mfma_f32_16x16x32_bf16(af, bf, a2, 0, 0, 0);
            }
            __syncthreads();
            const int col = ch * 16 + lm;
            const float bias = b2s[col];
            #pragma unroll
            for (int r = 0; r < 4; ++r)
                h2p[(r1 + q * 4 + r) * 36 + col] = fmaxf(a2[r] + bias, 0.f);
        }
        __syncthreads();

        // column sums
        {
            const int c = tid & 31;
            const int g = tid >> 5;
            float p0 = 0.f, p1 = 0.f;
            #pragma unroll
            for (int i = 0; i < 4; ++i) {
                const int r = g * 4 + i;
                if (row0 + r < 2 * NN) {
                    const float v = h2p[r * 36 + c];
                    if (r & 1) p1 += v; else p0 += v;
                }
            }
            if (p0 != 0.f) atomicAdd(&oacc[c], p0);
            if (p1 != 0.f) atomicAdd(&oacc[32 + c], p1);
        }
        __syncthreads();
        if (tid < 64) racc += oacc[tid];
    }
    if (tid < 64) partials[(size_t)bid * 64 + tid] = racc;

    gridbar(4, nb, barc, barm, barg);

    // ================= Phase E: reduce partials + final (64 blocks) ==========
    if (bid < 64) {
        const int t = tid & 63;
        float s = 0.f;
        for (int g = bid * 4 + wv; g < nb; g += 256)
            s += partials[(size_t)g * 64 + t];
        lsum[wv][t] = s;
        __syncthreads();
        if (tid < 64) {
            const float v = lsum[0][t] + lsum[1][t] + lsum[2][t] + lsum[3][t];
            unsafeAtomicAdd(&accum[t], v);
        }
        __threadfence();
        __syncthreads();
        if (tid == 0)
            lastf = (atomicAdd(dcnt, 1) == 63) ? 1 : 0;
        __syncthreads();
        if (lastf && tid < 2 * OO) {
            const int b = tid / OO, o = tid % OO;
            float acc = b3v[o];
            const float inv = 1.0f / (float)NN;
            #pragma unroll
            for (int j = 0; j < L2; ++j)
                acc += (unsafeAtomicAdd(&accum[b * 32 + j], 0.f) * inv) * W3[j * OO + o];
            out[tid] = acc;
        }
    }
}

// ===================== Fallback multi-kernel path (proven, r6) ===============
__global__ __launch_bounds__(256) void k_prep(
    const float* __restrict__ x, unsigned short* __restrict__ xb,
    const int* __restrict__ ei, int* __restrict__ counts,
    const float* __restrict__ W, const float* __restrict__ W1,
    const float* __restrict__ W2, unsigned short* __restrict__ wtp,
    unsigned short* __restrict__ w1tp, unsigned short* __restrict__ w2tp,
    int* __restrict__ ssf, int nfill, unsigned* __restrict__ zrow, int E)
{
    const int gid = blockIdx.x * 256 + threadIdx.x;
    const int stride = gridDim.x * 256;
    for (int i = gid; i < NWT; i += stride) {
        if (i < NW0) {
            const int e = i & 7, ln = (i >> 3) & 63, ks = (i >> 9) & 3, ct = i >> 11;
            wtp[i] = f2bf(W[(ks * 32 + (ln >> 4) * 8 + e) * HH + ct * 16 + (ln & 15)]);
        } else if (i < NW0 + NW1) {
            const int j = i - NW0;
            const int e = j & 7, ln = (j >> 3) & 63, ks = (j >> 9) & 3, ct = j >> 11;
            w1tp[j] = f2bf(W1[(ks * 32 + (ln >> 4) * 8 + e) * L1 + ct * 16 + (ln & 15)]);
        } else {
            const int j = i - NW0 - NW1;
            const int e = j & 7, ln = (j >> 3) & 63, ks = (j >> 9) & 1, ct = j >> 10;
            w2tp[j] = f2bf(W2[(ks * 32 + (ln >> 4) * 8 + e) * L2 + ct * 16 + (ln & 15)]);
        }
    }
    if (zrow != nullptr && gid < 128) zrow[gid] = 0u;
    for (int i = gid; i < nfill; i += stride) ssf[i] = NN;
    const int HALF = NN * 32;
    for (int idx = gid; idx < 2 * HALF; idx += stride) {
        const int b = (idx >= HALF) ? 1 : 0;
        const int j = idx - b * HALF;
        const int n = j >> 5;
        const int c4 = j & 31;
        const float4 v = *(const float4*)(x + ((size_t)b * NN + n) * DD + c4 * 4);
        ushort4 o;
        o.x = f2bf(v.x); o.y = f2bf(v.y); o.z = f2bf(v.z); o.w = f2bf(v.w);
        *(ushort4*)(xb + ((size_t)n * 2 + b) * DD + c4 * 4) = o;
    }
    for (int e = gid; e < E; e += stride)
        atomicAdd(&counts[ei[(size_t)E + e]], 1);
}

__global__ __launch_bounds__(1024) void k_scan1(
    const int* __restrict__ counts, int* __restrict__ offsets,
    int* __restrict__ blksum, int n)
{
    __shared__ int wsum[16], woff[16];
    const int tid = threadIdx.x, lane = tid & 63, wv = tid >> 6;
    const int i = blockIdx.x * 1024 + tid;
    int v = (i < n) ? ((counts[i] + 7) & ~7) : 0;
    int x = v;
    #pragma unroll
    for (int d = 1; d < 64; d <<= 1) { int t = __shfl_up(x, d); if (lane >= d) x += t; }
    if (lane == 63) wsum[wv] = x;
    __syncthreads();
    if (wv == 0 && lane < 16) {
        int y = wsum[lane];
        #pragma unroll
        for (int d = 1; d < 16; d <<= 1) { int t = __shfl_up(y, d); if (lane >= d) y += t; }
        woff[lane] = y - wsum[lane];
        if (lane == 15) blksum[blockIdx.x] = y;
    }
    __syncthreads();
    if (i < n) offsets[i] = woff[wv] + (x - v);
}

__global__ __launch_bounds__(1024) void k_scan2(
    int* __restrict__ offsets, const int* __restrict__ blksum, int nblk, int n)
{
    __shared__ int base_sh, tot_sh;
    const int tid = threadIdx.x, lane = tid & 63, wv = tid >> 6;
    if (wv == 0) {
        int v = (lane < nblk) ? blksum[lane] : 0;
        int x = v;
        #pragma unroll
        for (int d = 1; d < 64; d <<= 1) { int t = __shfl_up(x, d); if (lane >= d) x += t; }
        int incl = __shfl(x, blockIdx.x);
        int own  = __shfl(v, blockIdx.x);
        int tot  = __shfl(x, nblk - 1);
        if (lane == 0) { base_sh = incl - own; tot_sh = tot; }
    }
    __syncthreads();
    const int i = blockIdx.x * 1024 + tid;
    if (i < n) offsets[i] += base_sh;
    if (blockIdx.x == nblk - 1 && tid == 0) offsets[n] = tot_sh;
}

__global__ __launch_bounds__(256) void k_bucket(
    const int* __restrict__ ei, const int* __restrict__ offsets,
    int* __restrict__ cursor, int* __restrict__ ss, int E)
{
    int e = blockIdx.x * 256 + threadIdx.x;
    if (e < E) {
        int d = ei[E + e];
        int pos = offsets[d] + atomicAdd(&cursor[d], 1);
        ss[pos] = ei[e];
    }
}

template<bool FUSED>
__global__ __launch_bounds__(256, 8) void k_mlp_t(
    const unsigned short* __restrict__ src,
    const int* __restrict__ offsets, const int* __restrict__ ss,
    const unsigned short* __restrict__ wtp, const float* __restrict__ b0v,
    const unsigned short* __restrict__ w1tp, const float* __restrict__ b1v,
    const unsigned short* __restrict__ w2tp, const float* __restrict__ b2v,
    float* __restrict__ partials, int srows)
{
    __shared__ __align__(16) unsigned char upool[32 * 136 * 2];
    __shared__ __align__(16) unsigned short h1b[32 * 72];
    __shared__ float b0s[DD], b1s[L1], b2s[L2];
    __shared__ float oacc[64];
    unsigned short* xa  = (unsigned short*)upool;
    unsigned short* hsb = (unsigned short*)upool;
    float* h2p = (float*)upool;

    const int tid = threadIdx.x;
    const int row0 = blockIdx.x * 32;
    const int lane = tid & 63;
    const int w = tid >> 6;

    if (tid < DD) b0s[tid] = b0v[tid];
    if (tid < L1) b1s[tid] = b1v[tid];
    if (tid < L2) b2s[tid] = b2v[tid];
    if (tid < 64) oacc[tid] = 0.f;

    if (FUSED) {
        const int half4 = (lane >> 5) * 4;
        const int co = (lane & 31) * 8;
        #pragma unroll
        for (int j = 0; j < 4; ++j) {
            const int ln = w * 4 + j;
            const int d = blockIdx.x * 16 + ln;
            int s0 = 0, s1 = 0;
            if (d < NN) { s0 = offsets[d]; s1 = offsets[d + 1]; }
            float a[8];
            #pragma unroll
            for (int t = 0; t < 8; ++t) a[t] = 0.f;
            uint4 nidx;
            if (s0 < s1) nidx = *(const uint4*)(ss + s0 + half4);
            for (int i = s0; i < s1; ) {
                const uint4 idx = nidx;
                const int inext = i + 8;
                if (inext < s1) nidx = *(const uint4*)(ss + inext + half4);
                const uint4 r0 = *(const uint4*)(src + (size_t)idx.x * 256 + co);
                const uint4 r1 = *(const uint4*)(src + (size_t)idx.y * 256 + co);
                const uint4 r2 = *(const uint4*)(src + (size_t)idx.z * 256 + co);
                const uint4 r3 = *(const uint4*)(src + (size_t)idx.w * 256 + co);
                a[0] += bf2f_lo(r0.x); a[1] += bf2f_hi(r0.x);
                a[2] += bf2f_lo(r0.y); a[3] += bf2f_hi(r0.y);
                a[4] += bf2f_lo(r0.z); a[5] += bf2f_hi(r0.z);
                a[6] += bf2f_lo(r0.w); a[7] += bf2f_hi(r0.w);
                a[0] += bf2f_lo(r1.x); a[1] += bf2f_hi(r1.x);
                a[2] += bf2f_lo(r1.y); a[3] += bf2f_hi(r1.y);
                a[4] += bf2f_lo(r1.z); a[5] += bf2f_hi(r1.z);
                a[6] += bf2f_lo(r1.w); a[7] += bf2f_hi(r1.w);
                a[0] += bf2f_lo(r2.x); a[1] += bf2f_hi(r2.x);
                a[2] += bf2f_lo(r2.y); a[3] += bf2f_hi(r2.y);
                a[4] += bf2f_lo(r2.z); a[5] += bf2f_hi(r2.z);
                a[6] += bf2f_lo(r2.w); a[7] += bf2f_hi(r2.w);
                a[0] += bf2f_lo(r3.x); a[1] += bf2f_hi(r3.x);
                a[2] += bf2f_lo(r3.y); a[3] += bf2f_hi(r3.y);
                a[4] += bf2f_lo(r3.z); a[5] += bf2f_hi(r3.z);
                a[6] += bf2f_lo(r3.w); a[7] += bf2f_hi(r3.w);
                i = inext;
            }
            #pragma unroll
            for (int t = 0; t < 8; ++t) a[t] += __shfl_xor(a[t], 32);
            if (lane < 32) {
                const int tr = ln * 2 + (lane >> 4);
                const int col = (lane & 15) * 8;
                uint4 o;
                o.x = pack2(a[0], a[1]); o.y = pack2(a[2], a[3]);
                o.z = pack2(a[4], a[5]); o.w = pack2(a[6], a[7]);
                *(uint4*)(&xa[tr * 136 + col]) = o;
            }
        }
    } else {
        for (int u = tid * 8; u < 32 * DD; u += 2048) {
            const int r = u >> 7, c = u & 127;
            uint4 raw = make_uint4(0, 0, 0, 0);
            if (row0 + r < srows) raw = *(const uint4*)(src + (size_t)(row0 + r) * HH + c);
            *(uint4*)(&xa[r * 136 + c]) = raw;
        }
    }
    __syncthreads();

    const int lm = lane & 15;
    const int q = lane >> 4;
    const int r1 = (w & 1) * 16;
    const int ch = w >> 1;

    {
        v4f acc[4];
        #pragma unroll
        for (int i = 0; i < 4; ++i) acc[i] = (v4f)(0.f);
        #pragma unroll
        for (int ks = 0; ks < 4; ++ks) {
            const int k0 = ks * 32 + q * 8;
            const v8s af = *(const v8s*)(&xa[(r1 + lm) * 136 + k0]);
            #pragma unroll
            for (int ct = 0; ct < 4; ++ct) {
                const int ctg = ch * 4 + ct;
                const v8s bf = *(const v8s*)(wtp + ((size_t)(ctg * 4 + ks) * 64 + lane) * 8);
                acc[ct] = __builtin_amdgcn_mfma_f32_16x16x32_bf16(af, bf, acc[ct], 0, 0, 0);
            }
        }
        __syncthreads();
        #pragma unroll
        for (int ct = 0; ct < 4; ++ct) {
            const int col = ch * 64 + ct * 16 + lm;
            const float bias = b0s[col];
            #pragma unroll
            for (int r = 0; r < 4; ++r)
                hsb[(r1 + q * 4 + r) * 136 + col] = f2bf(gelu_f(acc[ct][r] + bias));
        }
    }
    __syncthreads();

    {
        v4f a1[2];
        a1[0] = (v4f)(0.f); a1[1] = (v4f)(0.f);
        #pragma unroll
        for (int ks = 0; ks < 4; ++ks) {
            const int k0 = ks * 32 + q * 8;
            const v8s af = *(const v8s*)(&hsb[(r1 + lm) * 136 + k0]);
            #pragma unroll
            for (int ct = 0; ct < 2; ++ct) {
                const int ctg = ch * 2 + ct;
                const v8s bf = *(const v8s*)(w1tp + ((size_t)(ctg * 4 + ks) * 64 + lane) * 8);
                a1[ct] = __builtin_amdgcn_mfma_f32_16x16x32_bf16(af, bf, a1[ct], 0, 0, 0);
            }
        }
        #pragma unroll
        for (int ct = 0; ct < 2; ++ct) {
            const int col = ch * 32 + ct * 16 + lm;
            const float bias = b1s[col];
            #pragma unroll
            for (int r = 0; r < 4; ++r)
                h1b[(r1 + q * 4 + r) * 72 + col] = f2bf(fmaxf(a1[ct][r] + bias, 0.f));
        }
    }
    __syncthreads();

    {
        v4f a2 = (v4f)(0.f);
        #pragma unroll
        for (int ks = 0; ks < 2; ++ks) {
            const int k0 = ks * 32 + q * 8;
            const v8s af = *(const v8s*)(&h1b[(r1 + lm) * 72 + k0]);
            const v8s bf = *(const v8s*)(w2tp + ((size_t)(ch * 2 + ks) * 64 + lane) * 8);
            a2 = __builtin_amdgcn_mfma_f32_16x16x32_bf16(af, bf, a2, 0, 0, 0);
        }
        __syncthreads();
        const int col = ch * 16 + lm;
        const float bias = b2s[col];
        #pragma unroll
        for (int r = 0; r < 4; ++r)
            h2p[(r1 + q * 4 + r) * 36 + col] = fmaxf(a2[r] + bias, 0.f);
    }
    __syncthreads();

    {
        const int c = tid & 31;
        const int g = tid >> 5;
        float p0 = 0.f, p1 = 0.f;
        #pragma unroll
        for (int i = 0; i < 4; ++i) {
            const int r = g * 4 + i;
            if (row0 + r < srows) {
                const float v = h2p[r * 36 + c];
                if (r & 1) p1 += v; else p0 += v;
            }
        }
        if (p0 != 0.f) atomicAdd(&oacc[c], p0);
        if (p1 != 0.f) atomicAdd(&oacc[32 + c], p1);
    }
    __syncthreads();
    if (tid < 64) partials[(size_t)blockIdx.x * 64 + tid] = oacc[tid];
}

__global__ __launch_bounds__(256) void k_scatter(
    const int* __restrict__ ei, const unsigned short* __restrict__ xb,
    float* __restrict__ aggf, int E)
{
    const int tid = threadIdx.x;
    const int eg = tid >> 6;
    const int lane = tid & 63;
    const int e = blockIdx.x * 4 + eg;
    if (e >= E) return;
    const int src = ei[e];
    const int dst = ei[E + e];
    const uint2 r = *(const uint2*)(xb + (size_t)src * 256 + lane * 4);
    float* ap = aggf + (size_t)dst * 256 + lane * 4;
    unsafeAtomicAdd(ap + 0, bf2f_lo(r.x));
    unsafeAtomicAdd(ap + 1, bf2f_hi(r.x));
    unsafeAtomicAdd(ap + 2, bf2f_lo(r.y));
    unsafeAtomicAdd(ap + 3, bf2f_hi(r.y));
}

__global__ __launch_bounds__(256) void k_cvt(
    const float* __restrict__ in, unsigned short* __restrict__ outb, int n)
{
    int i = blockIdx.x * 256 + threadIdx.x;
    if (i < n) outb[i] = f2bf(in[i]);
}

__global__ __launch_bounds__(256) void k_reduce_final(
    const float* __restrict__ partials, float* __restrict__ accum, int nblk,
    int* __restrict__ dcnt, const float* __restrict__ W3,
    const float* __restrict__ b3v, float* __restrict__ out)
{
    __shared__ float lsum[4][64];
    __shared__ int lastf;
    const int t = threadIdx.x & 63;
    const int w = threadIdx.x >> 6;
    float s = 0.f;
    for (int g = blockIdx.x * 4 + w; g < nblk; g += gridDim.x * 4)
        s += partials[(size_t)g * 64 + t];
    lsum[w][t] = s;
    __syncthreads();
    if (threadIdx.x < 64) {
        const float v = lsum[0][t] + lsum[1][t] + lsum[2][t] + lsum[3][t];
        unsafeAtomicAdd(&accum[t], v);
    }
    __threadfence();
    __syncthreads();
    if (threadIdx.x == 0)
        lastf = (atomicAdd(dcnt, 1) == (int)gridDim.x - 1) ? 1 : 0;
    __syncthreads();
    if (lastf && threadIdx.x < 2 * OO) {
        const int b = threadIdx.x / OO, o = threadIdx.x % OO;
        float acc = b3v[o];
        const float inv = 1.0f / (float)NN;
        #pragma unroll
        for (int j = 0; j < L2; ++j)
            acc += (unsafeAtomicAdd(&accum[b * 32 + j], 0.f) * inv) * W3[j * OO + o];
        out[threadIdx.x] = acc;
    }
}

extern "C" void kernel_launch(void* const* d_in, const int* in_sizes, int n_in,
                              void* d_out, int out_size, void* d_ws, size_t ws_size,
                              hipStream_t stream) {
    const float* x  = (const float*)d_in[0];
    const int*   ei = (const int*)d_in[1];
    const float* W  = (const float*)d_in[2];
    const float* b0 = (const float*)d_in[3];
    const float* W1 = (const float*)d_in[4];
    const float* b1 = (const float*)d_in[5];
    const float* W2 = (const float*)d_in[6];
    const float* b2 = (const float*)d_in[7];
    const float* W3 = (const float*)d_in[8];
    const float* b3 = (const float*)d_in[9];
    float* out = (float*)d_out;

    const int E = in_sizes[1] / 2;           // 800000
    const int rows = 2 * NN;                 // 100000 storage rows
    const int NT = (rows + 31) / 32;         // 3125 mlp tiles
    const int nsb = (NN + 1023) / 1024;      // 49 scan blocks (fallback)
    const int SSN = E + 7 * NN + 8;          // padded CSR capacity

    // ---- persistent-grid sizing (cached; co-residency guaranteed) ----
    static int s_grid = 0;
    static bool s_init = false;
    if (!s_init) {
        int occ = 0;
        hipDeviceProp_t prop;
        if (hipOccupancyMaxActiveBlocksPerMultiprocessor(&occ, k_mega, 256, 0) == hipSuccess &&
            hipGetDeviceProperties(&prop, 0) == hipSuccess && occ >= 1) {
            if (occ > 8) occ = 8;
            int g = (occ * prop.multiProcessorCount - 64) & ~31;   // 64-block safety margin
            if (g > MAXGRID) g = MAXGRID;
            if (g >= 256) s_grid = g;
        }
        s_init = true;
    }

    // ---- mega-path workspace layout ----
    unsigned short* xb = (unsigned short*)d_ws;                      // rows*HH bf16
    unsigned* zrow     = (unsigned*)(xb + (size_t)rows * HH);        // 512 B zero row
    int*   ss       = (int*)(zrow + 128);                            // SSN
    float* accum    = (float*)(ss + SSN);                            // 64   <- zero from here
    int*   dcnt     = (int*)(accum + 64);                            // 16
    int*   barc     = dcnt + 16;                                     // 512
    int*   barm     = barc + 512;                                    // 16
    int*   barg     = barm + 16;                                     // 16
    int*   wtotb    = barg + 16;                                     // 16
    int*   counts   = wtotb + 16;                                    // NN
    int*   cursor   = counts + NN;                                   // NN  <- zero to here
    int*   offsets  = cursor + NN;                                   // NN+1
    int*   blksum   = offsets + NN + 1;                              // 256
    int*   blkoff   = blksum + 256;                                  // 256
    float* partials = (float*)(blkoff + 256);                        // MAXGRID*64
    unsigned short* wtp = (unsigned short*)(((uintptr_t)(partials + (size_t)MAXGRID * 64) + 15) & ~(uintptr_t)15);
    unsigned short* w1tp = wtp + NW0;
    unsigned short* w2tp = w1tp + NW1;
    const size_t need_mega = (size_t)((char*)(w2tp + NW2) - (char*)d_ws) + 16;
    const size_t zeroN = 64 + 16 + 512 + 16 + 16 + 16 + 2 * (size_t)NN;   // ints

    if (s_grid > 0 && ws_size >= need_mega) {
        hipMemsetAsync(accum, 0, zeroN * sizeof(int), stream);
        k_mega<<<dim3(s_grid), dim3(256), 0, stream>>>(
            x, ei, W, W1, W2, W3, b0, b1, b2, b3, out,
            xb, zrow, ss, counts, cursor, offsets, blksum, blkoff, wtotb,
            partials, accum, dcnt, barc, barm, barg,
            wtp, w1tp, w2tp, E, SSN, NT);
        return;
    }

    // ---- fallback CSR multi-kernel path (r6 layout) ----
    {
        unsigned short* f_xb = (unsigned short*)d_ws;
        unsigned* f_zrow     = (unsigned*)(f_xb + (size_t)rows * HH);
        int*   f_ss       = (int*)(f_zrow + 128);
        float* f_partials = (float*)(f_ss + SSN);
        float* f_accum    = f_partials + (size_t)NT * 64;
        int*   f_dcnt     = (int*)(f_accum + 64);
        int*   f_counts   = f_dcnt + 16;
        int*   f_cursor   = f_counts + NN;
        int*   f_offsets  = f_cursor + NN;
        int*   f_blksum   = f_offsets + NN + 1;
        unsigned short* f_wtp = (unsigned short*)(((uintptr_t)(f_blksum + 64) + 15) & ~(uintptr_t)15);
        unsigned short* f_w1tp = f_wtp + NW0;
        unsigned short* f_w2tp = f_w1tp + NW1;
        const size_t need_csr = (size_t)((char*)(f_w2tp + NW2) - (char*)d_ws) + 16;

        unsigned short* g_aggb = f_xb + (size_t)rows * HH;
        float* g_partials = (float*)(g_aggb + (size_t)rows * HH);
        float* g_accum    = g_partials + (size_t)NT * 64;
        int*   g_dcnt     = (int*)(g_accum + 64);
        unsigned short* g_wtp = (unsigned short*)(((uintptr_t)(g_dcnt + 16) + 15) & ~(uintptr_t)15);
        unsigned short* g_w1tp = g_wtp + NW0;
        unsigned short* g_w2tp = g_w1tp + NW1;
        float* g_aggf     = (float*)(((uintptr_t)(g_w2tp + NW2) + 15) & ~(uintptr_t)15);
        const size_t need_fb = (size_t)((char*)(g_aggf + (size_t)rows * HH) - (char*)d_ws) + 16;

        if (ws_size >= need_csr && nsb <= 64) {
            hipMemsetAsync(f_accum, 0, (80 + 2 * (size_t)NN) * sizeof(int), stream);
            k_prep<<<dim3(2048), dim3(256), 0, stream>>>(
                x, f_xb, ei, f_counts, W, W1, W2, f_wtp, f_w1tp, f_w2tp, f_ss, SSN, f_zrow, E);
            k_scan1<<<dim3(nsb), dim3(1024), 0, stream>>>(f_counts, f_offsets, f_blksum, NN);
            k_scan2<<<dim3(nsb), dim3(1024), 0, stream>>>(f_offsets, f_blksum, nsb, NN);
            k_bucket<<<dim3((E + 255) / 256), dim3(256), 0, stream>>>(ei, f_offsets, f_cursor, f_ss, E);
            k_mlp_t<true><<<dim3(NT), dim3(256), 0, stream>>>(
                f_xb, f_offsets, f_ss, f_wtp, b0, f_w1tp, b1, f_w2tp, b2, f_partials, rows);
            k_reduce_final<<<dim3(64), dim3(256), 0, stream>>>(
                f_partials, f_accum, NT, f_dcnt, W3, b3, out);
        } else if (ws_size >= need_fb) {
            hipMemsetAsync(g_accum, 0, 80 * sizeof(int), stream);
            hipMemsetAsync(g_aggf, 0, (size_t)rows * HH * sizeof(float), stream);
            k_prep<<<dim3(2048), dim3(256), 0, stream>>>(
                x, f_xb, ei, g_dcnt, W, W1, W2, g_wtp, g_w1tp, g_w2tp,
                g_dcnt, 0, nullptr, 0);
            k_scatter<<<dim3((E + 3) / 4), dim3(256), 0, stream>>>(ei, f_xb, g_aggf, E);
            k_cvt<<<dim3((rows * HH + 255) / 256), dim3(256), 0, stream>>>(g_aggf, g_aggb, rows * HH);
            k_mlp_t<false><<<dim3(NT), dim3(256), 0, stream>>>(
                g_aggb, nullptr, nullptr, g_wtp, b0, g_w1tp, b1, g_w2tp, b2, g_partials, rows);
            k_reduce_final<<<dim3(64), dim3(256), 0, stream>>>(
                g_partials, g_accum, NT, g_dcnt, W3, b3, out);
        }
    }
}

// Round 11
// 706.152 us; speedup vs baseline: 1.5913x; 1.5913x over previous
//
#include <hip/hip_runtime.h>
#include <math.h>

#define NN 50000
#define DD 128
#define HH 128
#define L1 64
#define L2 32
#define OO 10

// packed B-fragment table sizes (ct * ks * 64 lanes * 8 elems)
#define NW0 16384   // W : 8 ct * 4 ks * 64 * 8
#define NW1 8192    // W1: 4 ct * 4 ks * 64 * 8
#define NW2 2048    // W2: 2 ct * 2 ks * 64 * 8
#define NWT (NW0 + NW1 + NW2)

typedef short v8s __attribute__((ext_vector_type(8)));   // 8 bf16 (4 VGPRs)
typedef float v4f __attribute__((ext_vector_type(4)));   // MFMA accumulator

// ---- bf16 helpers (manual: RNE pack) ----
__device__ __forceinline__ float bf2f_lo(unsigned u) { return __uint_as_float(u << 16); }
__device__ __forceinline__ float bf2f_hi(unsigned u) { return __uint_as_float(u & 0xffff0000u); }
__device__ __forceinline__ unsigned short f2bf(float f) {
    unsigned u = __float_as_uint(f);
    return (unsigned short)((u + 0x7fffu + ((u >> 16) & 1u)) >> 16);
}
__device__ __forceinline__ unsigned pack2(float lo, float hi) {
    return (unsigned)f2bf(lo) | ((unsigned)f2bf(hi) << 16);
}
__device__ __forceinline__ float gelu_f(float v) {
    return 0.5f * v * (1.f + erff(v * 0.70710678118654752f));
}

// ---------------- K1: weights pack + x->bf16 interleave + histogram + ss fill --
__global__ __launch_bounds__(256) void k_prep(
    const float* __restrict__ x, unsigned short* __restrict__ xb,
    const int* __restrict__ ei, int* __restrict__ counts,
    const float* __restrict__ W, const float* __restrict__ W1,
    const float* __restrict__ W2, unsigned short* __restrict__ wtp,
    unsigned short* __restrict__ w1tp, unsigned short* __restrict__ w2tp,
    int* __restrict__ ssf, int nfill, unsigned* __restrict__ zrow, int E)
{
    const int gid = blockIdx.x * 256 + threadIdx.x;
    const int stride = gridDim.x * 256;
    for (int i = gid; i < NWT; i += stride) {
        if (i < NW0) {
            const int e = i & 7, ln = (i >> 3) & 63, ks = (i >> 9) & 3, ct = i >> 11;
            wtp[i] = f2bf(W[(ks * 32 + (ln >> 4) * 8 + e) * HH + ct * 16 + (ln & 15)]);
        } else if (i < NW0 + NW1) {
            const int j = i - NW0;
            const int e = j & 7, ln = (j >> 3) & 63, ks = (j >> 9) & 3, ct = j >> 11;
            w1tp[j] = f2bf(W1[(ks * 32 + (ln >> 4) * 8 + e) * L1 + ct * 16 + (ln & 15)]);
        } else {
            const int j = i - NW0 - NW1;
            const int e = j & 7, ln = (j >> 3) & 63, ks = (j >> 9) & 1, ct = j >> 10;
            w2tp[j] = f2bf(W2[(ks * 32 + (ln >> 4) * 8 + e) * L2 + ct * 16 + (ln & 15)]);
        }
    }
    if (zrow != nullptr && gid < 128) zrow[gid] = 0u;
    for (int i = gid; i < nfill; i += stride) ssf[i] = NN;
    const int HALF = NN * 32;
    for (int idx = gid; idx < 2 * HALF; idx += stride) {
        const int b = (idx >= HALF) ? 1 : 0;
        const int j = idx - b * HALF;
        const int n = j >> 5;
        const int c4 = j & 31;
        const float4 v = *(const float4*)(x + ((size_t)b * NN + n) * DD + c4 * 4);
        ushort4 o;
        o.x = f2bf(v.x); o.y = f2bf(v.y); o.z = f2bf(v.z); o.w = f2bf(v.w);
        *(ushort4*)(xb + ((size_t)n * 2 + b) * DD + c4 * 4) = o;
    }
    for (int e = gid; e < E; e += stride)
        atomicAdd(&counts[ei[(size_t)E + e]], 1);
}

// ---------------- K2: fused two-level scan (8-padded degrees) ----------------
// 49 blocks x 1024. Chunk-local exclusive offsets + blksum; the LAST-arriving
// block (done-counter, non-blocking — nobody waits) scans the 49 chunk sums
// into blkoff[] + grand total. Downstream kernels add blkoff[d>>10].
__global__ __launch_bounds__(1024) void k_scanA(
    const int* __restrict__ counts, int* __restrict__ offsets,
    int* __restrict__ blksum, int* __restrict__ blkoff,
    int* __restrict__ wtotb, int* __restrict__ scnt, int n, int nblk)
{
    __shared__ int wsum[16], woff[16];
    __shared__ int lastf;
    const int tid = threadIdx.x, lane = tid & 63, wv = tid >> 6;
    const int i = blockIdx.x * 1024 + tid;
    int v = (i < n) ? ((counts[i] + 7) & ~7) : 0;
    int x = v;
    #pragma unroll
    for (int d = 1; d < 64; d <<= 1) { int t = __shfl_up(x, d); if (lane >= d) x += t; }
    if (lane == 63) wsum[wv] = x;
    __syncthreads();
    if (wv == 0 && lane < 16) {
        int y = wsum[lane];
        #pragma unroll
        for (int d = 1; d < 16; d <<= 1) { int t = __shfl_up(y, d); if (lane >= d) y += t; }
        woff[lane] = y - wsum[lane];
        if (lane == 15) blksum[blockIdx.x] = y;
    }
    __syncthreads();
    if (i < n) offsets[i] = woff[wv] + (x - v);

    // non-blocking last-block chunk-sum scan
    __threadfence();                       // release blksum write
    __syncthreads();
    if (tid == 0)
        lastf = (atomicAdd(scnt, 1) == nblk - 1) ? 1 : 0;
    __syncthreads();
    if (lastf && wv == 0) {
        int s = (lane < nblk) ? atomicAdd(&blksum[lane], 0) : 0;   // coherent read
        int xx = s;
        #pragma unroll
        for (int d = 1; d < 64; d <<= 1) { int t = __shfl_up(xx, d); if (lane >= d) xx += t; }
        if (lane < nblk) blkoff[lane] = xx - s;        // exclusive
        if (lane == nblk - 1) wtotb[0] = xx;           // grand total
    }
}

// ---------------- K3: CSR build: bucket src indices by dst ----------------
__global__ __launch_bounds__(256) void k_bucket(
    const int* __restrict__ ei, const int* __restrict__ offsets,
    const int* __restrict__ blkoff, int* __restrict__ cursor,
    int* __restrict__ ss, int E)
{
    int e = blockIdx.x * 256 + threadIdx.x;
    if (e < E) {
        int d = ei[E + e];
        int pos = offsets[d] + blkoff[d >> 10] + atomicAdd(&cursor[d], 1);
        ss[pos] = ei[e];
    }
}

// ---------------- K4: fused gather-agg + (agg@W) + gelu + MLP + colsums
//                      + LAST-BLOCK reduce + layer3 (done-counter, no spin) ---
// Block: 16 nodes (32 storage rows), 256 threads (4 waves).
template<bool FUSED>
__global__ __launch_bounds__(256, 8) void k_mlp_t(
    const unsigned short* __restrict__ src,   // FUSED ? xb : aggb
    const int* __restrict__ offsets, const int* __restrict__ ss,
    const int* __restrict__ blkoff, const int* __restrict__ wtotb,
    const unsigned short* __restrict__ wtp, const float* __restrict__ b0v,
    const unsigned short* __restrict__ w1tp, const float* __restrict__ b1v,
    const unsigned short* __restrict__ w2tp, const float* __restrict__ b2v,
    float* __restrict__ partials, int srows,
    int* __restrict__ dcnt, const float* __restrict__ W3,
    const float* __restrict__ b3v, float* __restrict__ out)
{
    __shared__ __align__(16) unsigned char upool[32 * 136 * 2]; // xa/hsb/h2p
    __shared__ __align__(16) unsigned short h1b[32 * 72];       // 4.6 KB
    __shared__ float b0s[DD], b1s[L1], b2s[L2];
    __shared__ float oacc[64];
    __shared__ float lsum[4][64];
    __shared__ int lastf;
    unsigned short* xa  = (unsigned short*)upool;   // [32][136] bf16 agg tile
    unsigned short* hsb = (unsigned short*)upool;   // [32][136] bf16 (after xa dead)
    float* h2p = (float*)upool;                     // [32][36] f32 (after hsb dead)

    const int tid = threadIdx.x;
    const int row0 = blockIdx.x * 32;
    const int lane = tid & 63;
    const int w = tid >> 6;       // 0..3

    if (tid < DD) b0s[tid] = b0v[tid];
    if (tid < L1) b1s[tid] = b1v[tid];
    if (tid < L2) b2s[tid] = b2v[tid];
    if (tid < 64) oacc[tid] = 0.f;

    if (FUSED) {
        const int half4 = (lane >> 5) * 4;         // 0 | 4
        const int co = (lane & 31) * 8;            // shorts offset in 512B row
        const int wtot = wtotb[0];
        #pragma unroll
        for (int j = 0; j < 4; ++j) {
            const int ln = w * 4 + j;              // block-local node 0..15
            const int d = blockIdx.x * 16 + ln;    // global node
            int s0 = 0, s1 = 0;
            if (d < NN) {
                s0 = offsets[d] + blkoff[d >> 10];
                s1 = (d + 1 < NN) ? offsets[d + 1] + blkoff[(d + 1) >> 10] : wtot;
            }
            float a[8];
            #pragma unroll
            for (int t = 0; t < 8; ++t) a[t] = 0.f;
            uint4 nidx;
            if (s0 < s1) nidx = *(const uint4*)(ss + s0 + half4);
            for (int i = s0; i < s1; ) {
                const uint4 idx = nidx;
                const int inext = i + 8;
                if (inext < s1) nidx = *(const uint4*)(ss + inext + half4);
                const uint4 r0 = *(const uint4*)(src + (size_t)idx.x * 256 + co);
                const uint4 r1 = *(const uint4*)(src + (size_t)idx.y * 256 + co);
                const uint4 r2 = *(const uint4*)(src + (size_t)idx.z * 256 + co);
                const uint4 r3 = *(const uint4*)(src + (size_t)idx.w * 256 + co);
                a[0] += bf2f_lo(r0.x); a[1] += bf2f_hi(r0.x);
                a[2] += bf2f_lo(r0.y); a[3] += bf2f_hi(r0.y);
                a[4] += bf2f_lo(r0.z); a[5] += bf2f_hi(r0.z);
                a[6] += bf2f_lo(r0.w); a[7] += bf2f_hi(r0.w);
                a[0] += bf2f_lo(r1.x); a[1] += bf2f_hi(r1.x);
                a[2] += bf2f_lo(r1.y); a[3] += bf2f_hi(r1.y);
                a[4] += bf2f_lo(r1.z); a[5] += bf2f_hi(r1.z);
                a[6] += bf2f_lo(r1.w); a[7] += bf2f_hi(r1.w);
                a[0] += bf2f_lo(r2.x); a[1] += bf2f_hi(r2.x);
                a[2] += bf2f_lo(r2.y); a[3] += bf2f_hi(r2.y);
                a[4] += bf2f_lo(r2.z); a[5] += bf2f_hi(r2.z);
                a[6] += bf2f_lo(r2.w); a[7] += bf2f_hi(r2.w);
                a[0] += bf2f_lo(r3.x); a[1] += bf2f_hi(r3.x);
                a[2] += bf2f_lo(r3.y); a[3] += bf2f_hi(r3.y);
                a[4] += bf2f_lo(r3.z); a[5] += bf2f_hi(r3.z);
                a[6] += bf2f_lo(r3.w); a[7] += bf2f_hi(r3.w);
                i = inext;
            }
            #pragma unroll
            for (int t = 0; t < 8; ++t) a[t] += __shfl_xor(a[t], 32);
            if (lane < 32) {
                const int tr = ln * 2 + (lane >> 4);   // storage row in tile
                const int col = (lane & 15) * 8;
                uint4 o;
                o.x = pack2(a[0], a[1]); o.y = pack2(a[2], a[3]);
                o.z = pack2(a[4], a[5]); o.w = pack2(a[6], a[7]);
                *(uint4*)(&xa[tr * 136 + col]) = o;
            }
        }
    } else {
        for (int u = tid * 8; u < 32 * DD; u += 2048) {
            const int r = u >> 7, c = u & 127;
            uint4 raw = make_uint4(0, 0, 0, 0);
            if (row0 + r < srows) raw = *(const uint4*)(src + (size_t)(row0 + r) * HH + c);
            *(uint4*)(&xa[r * 136 + c]) = raw;
        }
    }
    __syncthreads();

    const int lm = lane & 15;
    const int q = lane >> 4;
    const int r1 = (w & 1) * 16;  // row-tile base (0/16)
    const int ch = w >> 1;        // column half 0/1

    // W-GEMM (32x128 @ 128x128)
    {
        v4f acc[4];
        #pragma unroll
        for (int i = 0; i < 4; ++i) acc[i] = (v4f)(0.f);
        #pragma unroll
        for (int ks = 0; ks < 4; ++ks) {
            const int k0 = ks * 32 + q * 8;
            const v8s af = *(const v8s*)(&xa[(r1 + lm) * 136 + k0]);
            #pragma unroll
            for (int ct = 0; ct < 4; ++ct) {
                const int ctg = ch * 4 + ct;
                const v8s bf = *(const v8s*)(wtp + ((size_t)(ctg * 4 + ks) * 64 + lane) * 8);
                acc[ct] = __builtin_amdgcn_mfma_f32_16x16x32_bf16(af, bf, acc[ct], 0, 0, 0);
            }
        }
        __syncthreads();   // xa reads done; upool becomes hsb
        #pragma unroll
        for (int ct = 0; ct < 4; ++ct) {
            const int col = ch * 64 + ct * 16 + lm;
            const float bias = b0s[col];
            #pragma unroll
            for (int r = 0; r < 4; ++r)
                hsb[(r1 + q * 4 + r) * 136 + col] = f2bf(gelu_f(acc[ct][r] + bias));
        }
    }
    __syncthreads();

    // layer1 (32x128 @ 128x64)
    {
        v4f a1[2];
        a1[0] = (v4f)(0.f); a1[1] = (v4f)(0.f);
        #pragma unroll
        for (int ks = 0; ks < 4; ++ks) {
            const int k0 = ks * 32 + q * 8;
            const v8s af = *(const v8s*)(&hsb[(r1 + lm) * 136 + k0]);
            #pragma unroll
            for (int ct = 0; ct < 2; ++ct) {
                const int ctg = ch * 2 + ct;
                const v8s bf = *(const v8s*)(w1tp + ((size_t)(ctg * 4 + ks) * 64 + lane) * 8);
                a1[ct] = __builtin_amdgcn_mfma_f32_16x16x32_bf16(af, bf, a1[ct], 0, 0, 0);
            }
        }
        #pragma unroll
        for (int ct = 0; ct < 2; ++ct) {
            const int col = ch * 32 + ct * 16 + lm;
            const float bias = b1s[col];
            #pragma unroll
            for (int r = 0; r < 4; ++r)
                h1b[(r1 + q * 4 + r) * 72 + col] = f2bf(fmaxf(a1[ct][r] + bias, 0.f));
        }
    }
    __syncthreads();

    // layer2 (32x64 @ 64x32)
    {
        v4f a2 = (v4f)(0.f);
        #pragma unroll
        for (int ks = 0; ks < 2; ++ks) {
            const int k0 = ks * 32 + q * 8;
            const v8s af = *(const v8s*)(&h1b[(r1 + lm) * 72 + k0]);
            const v8s bf = *(const v8s*)(w2tp + ((size_t)(ch * 2 + ks) * 64 + lane) * 8);
            a2 = __builtin_amdgcn_mfma_f32_16x16x32_bf16(af, bf, a2, 0, 0, 0);
        }
        __syncthreads();   // hsb (upool) reads done; reuse as h2p
        const int col = ch * 16 + lm;
        const float bias = b2s[col];
        #pragma unroll
        for (int r = 0; r < 4; ++r)
            h2p[(r1 + q * 4 + r) * 36 + col] = fmaxf(a2[r] + bias, 0.f);
    }
    __syncthreads();

    // column sums: storage row r -> batch r&1
    {
        const int c = tid & 31;
        const int g = tid >> 5;   // 0..7, 4 rows each
        float p0 = 0.f, p1 = 0.f;
        #pragma unroll
        for (int i = 0; i < 4; ++i) {
            const int r = g * 4 + i;
            if (row0 + r < srows) {
                const float v = h2p[r * 36 + c];
                if (r & 1) p1 += v; else p0 += v;
            }
        }
        if (p0 != 0.f) atomicAdd(&oacc[c], p0);
        if (p1 != 0.f) atomicAdd(&oacc[32 + c], p1);
    }
    __syncthreads();
    if (tid < 64) partials[(size_t)blockIdx.x * 64 + tid] = oacc[tid];

    // ---- non-blocking last-block reduce + layer3 (proven done-counter) ----
    __threadfence();                      // release partials write
    __syncthreads();
    if (tid == 0)
        lastf = (atomicAdd(dcnt, 1) == (int)gridDim.x - 1) ? 1 : 0;
    __syncthreads();
    if (lastf) {
        const int t = tid & 63;
        const int NTb = (int)gridDim.x;
        float s = 0.f;
        for (int g = w; g < NTb; g += 4)
            s += unsafeAtomicAdd(&partials[(size_t)g * 64 + t], 0.f);   // coherent read
        lsum[w][t] = s;
        __syncthreads();
        if (tid < 64)
            oacc[t] = lsum[0][t] + lsum[1][t] + lsum[2][t] + lsum[3][t];
        __syncthreads();
        if (tid < 2 * OO) {
            const int b = tid / OO, o = tid % OO;
            float acc = b3v[o];
            const float inv = 1.0f / (float)NN;
            #pragma unroll
            for (int j = 0; j < L2; ++j)
                acc += (oacc[b * 32 + j] * inv) * W3[j * OO + o];
            out[tid] = acc;
        }
    }
}

// ---------------- Fallback path (ws too small for CSR) ----------------
__global__ __launch_bounds__(256) void k_scatter(
    const int* __restrict__ ei, const unsigned short* __restrict__ xb,
    float* __restrict__ aggf, int E)
{
    const int tid = threadIdx.x;
    const int eg = tid >> 6;
    const int lane = tid & 63;
    const int e = blockIdx.x * 4 + eg;
    if (e >= E) return;
    const int src = ei[e];
    const int dst = ei[E + e];
    const uint2 r = *(const uint2*)(xb + (size_t)src * 256 + lane * 4);
    float* ap = aggf + (size_t)dst * 256 + lane * 4;
    unsafeAtomicAdd(ap + 0, bf2f_lo(r.x));
    unsafeAtomicAdd(ap + 1, bf2f_hi(r.x));
    unsafeAtomicAdd(ap + 2, bf2f_lo(r.y));
    unsafeAtomicAdd(ap + 3, bf2f_hi(r.y));
}

__global__ __launch_bounds__(256) void k_cvt(
    const float* __restrict__ in, unsigned short* __restrict__ outb, int n)
{
    int i = blockIdx.x * 256 + threadIdx.x;
    if (i < n) outb[i] = f2bf(in[i]);
}

extern "C" void kernel_launch(void* const* d_in, const int* in_sizes, int n_in,
                              void* d_out, int out_size, void* d_ws, size_t ws_size,
                              hipStream_t stream) {
    const float* x  = (const float*)d_in[0];
    const int*   ei = (const int*)d_in[1];
    const float* W  = (const float*)d_in[2];
    const float* b0 = (const float*)d_in[3];
    const float* W1 = (const float*)d_in[4];
    const float* b1 = (const float*)d_in[5];
    const float* W2 = (const float*)d_in[6];
    const float* b2 = (const float*)d_in[7];
    const float* W3 = (const float*)d_in[8];
    const float* b3 = (const float*)d_in[9];
    float* out = (float*)d_out;

    const int E = in_sizes[1] / 2;           // 800000
    const int rows = 2 * NN;                 // 100000 storage rows
    const int NT = (rows + 31) / 32;         // 3125 mlp tiles
    const int nsc = (NN + 1023) / 1024;      // 49 scan chunks
    const int SSN = E + 7 * NN + 8;          // padded CSR capacity

    // ---- CSR-path workspace layout ----
    unsigned short* xb = (unsigned short*)d_ws;                      // rows*HH bf16
    unsigned* zrow     = (unsigned*)(xb + (size_t)rows * HH);        // 512 B zero row
    int*   ss       = (int*)(zrow + 128);                            // SSN
    float* partials = (float*)(ss + SSN);                            // NT*64
    int*   dcnt     = (int*)(partials + (size_t)NT * 64);            // 16  <- zero from here
    int*   scnt     = dcnt + 16;                                     // 16
    int*   counts   = scnt + 16;                                     // NN
    int*   cursor   = counts + NN;                                   // NN  <- zero to here
    int*   offsets  = cursor + NN;                                   // NN+1
    int*   blksum   = offsets + NN + 1;                              // 64
    int*   blkoff   = blksum + 64;                                   // 64
    int*   wtotb    = blkoff + 64;                                   // 16
    unsigned short* wtp = (unsigned short*)(((uintptr_t)(wtotb + 16) + 15) & ~(uintptr_t)15);
    unsigned short* w1tp = wtp + NW0;
    unsigned short* w2tp = w1tp + NW1;
    const size_t need_csr = (size_t)((char*)(w2tp + NW2) - (char*)d_ws) + 16;
    const size_t zeroN = 32 + 2 * (size_t)NN;   // dcnt,scnt,counts,cursor (ints)

    // ---- fallback workspace layout ----
    unsigned short* g_aggb = xb + (size_t)rows * HH;
    float* g_partials = (float*)(g_aggb + (size_t)rows * HH);
    int*   g_dcnt     = (int*)(g_partials + (size_t)NT * 64);
    unsigned short* g_wtp = (unsigned short*)(((uintptr_t)(g_dcnt + 16) + 15) & ~(uintptr_t)15);
    unsigned short* g_w1tp = g_wtp + NW0;
    unsigned short* g_w2tp = g_w1tp + NW1;
    float* g_aggf     = (float*)(((uintptr_t)(g_w2tp + NW2) + 15) & ~(uintptr_t)15);
    const size_t need_fb = (size_t)((char*)(g_aggf + (size_t)rows * HH) - (char*)d_ws) + 16;

    if (ws_size >= need_csr && nsc <= 49) {
        hipMemsetAsync(dcnt, 0, zeroN * sizeof(int), stream);
        k_prep<<<dim3(2048), dim3(256), 0, stream>>>(
            x, xb, ei, counts, W, W1, W2, wtp, w1tp, w2tp, ss, SSN, zrow, E);
        k_scanA<<<dim3(nsc), dim3(1024), 0, stream>>>(
            counts, offsets, blksum, blkoff, wtotb, scnt, NN, nsc);
        k_bucket<<<dim3((E + 255) / 256), dim3(256), 0, stream>>>(
            ei, offsets, blkoff, cursor, ss, E);
        k_mlp_t<true><<<dim3(NT), dim3(256), 0, stream>>>(
            xb, offsets, ss, blkoff, wtotb, wtp, b0, w1tp, b1, w2tp, b2,
            partials, rows, dcnt, W3, b3, out);
    } else if (ws_size >= need_fb) {
        hipMemsetAsync(g_dcnt, 0, 16 * sizeof(int), stream);
        hipMemsetAsync(g_aggf, 0, (size_t)rows * HH * sizeof(float), stream);
        k_prep<<<dim3(2048), dim3(256), 0, stream>>>(
            x, xb, ei, g_dcnt /*unused*/, W, W1, W2, g_wtp, g_w1tp, g_w2tp,
            g_dcnt, 0, nullptr, 0);
        k_scatter<<<dim3((E + 3) / 4), dim3(256), 0, stream>>>(ei, xb, g_aggf, E);
        k_cvt<<<dim3((rows * HH + 255) / 256), dim3(256), 0, stream>>>(g_aggf, g_aggb, rows * HH);
        k_mlp_t<false><<<dim3(NT), dim3(256), 0, stream>>>(
            g_aggb, nullptr, nullptr, nullptr, nullptr, g_wtp, b0, g_w1tp, b1,
            g_w2tp, b2, g_partials, rows, g_dcnt, W3, b3, out);
    }
}

// Round 12
// 289.180 us; speedup vs baseline: 3.8858x; 2.4419x over previous
//
#include <hip/hip_runtime.h>
#include <math.h>

#define NN 50000
#define DD 128
#define HH 128
#define L1 64
#define L2 32
#define OO 10

// packed B-fragment table sizes (ct * ks * 64 lanes * 8 elems)
#define NW0 16384   // W : 8 ct * 4 ks * 64 * 8
#define NW1 8192    // W1: 4 ct * 4 ks * 64 * 8
#define NW2 2048    // W2: 2 ct * 2 ks * 64 * 8
#define NWT (NW0 + NW1 + NW2)

typedef short v8s __attribute__((ext_vector_type(8)));   // 8 bf16 (4 VGPRs)
typedef float v4f __attribute__((ext_vector_type(4)));   // MFMA accumulator

// ---- bf16 helpers (manual: RNE pack) ----
__device__ __forceinline__ float bf2f_lo(unsigned u) { return __uint_as_float(u << 16); }
__device__ __forceinline__ float bf2f_hi(unsigned u) { return __uint_as_float(u & 0xffff0000u); }
__device__ __forceinline__ unsigned short f2bf(float f) {
    unsigned u = __float_as_uint(f);
    return (unsigned short)((u + 0x7fffu + ((u >> 16) & 1u)) >> 16);
}
__device__ __forceinline__ unsigned pack2(float lo, float hi) {
    return (unsigned)f2bf(lo) | ((unsigned)f2bf(hi) << 16);
}
__device__ __forceinline__ float gelu_f(float v) {
    return 0.5f * v * (1.f + erff(v * 0.70710678118654752f));
}

// ---------------- K1: weights pack + x->bf16 interleave + histogram + ss fill --
__global__ __launch_bounds__(256) void k_prep(
    const float* __restrict__ x, unsigned short* __restrict__ xb,
    const int* __restrict__ ei, int* __restrict__ counts,
    const float* __restrict__ W, const float* __restrict__ W1,
    const float* __restrict__ W2, unsigned short* __restrict__ wtp,
    unsigned short* __restrict__ w1tp, unsigned short* __restrict__ w2tp,
    int* __restrict__ ssf, int nfill, unsigned* __restrict__ zrow, int E)
{
    const int gid = blockIdx.x * 256 + threadIdx.x;
    const int stride = gridDim.x * 256;
    for (int i = gid; i < NWT; i += stride) {
        if (i < NW0) {
            const int e = i & 7, ln = (i >> 3) & 63, ks = (i >> 9) & 3, ct = i >> 11;
            wtp[i] = f2bf(W[(ks * 32 + (ln >> 4) * 8 + e) * HH + ct * 16 + (ln & 15)]);
        } else if (i < NW0 + NW1) {
            const int j = i - NW0;
            const int e = j & 7, ln = (j >> 3) & 63, ks = (j >> 9) & 3, ct = j >> 11;
            w1tp[j] = f2bf(W1[(ks * 32 + (ln >> 4) * 8 + e) * L1 + ct * 16 + (ln & 15)]);
        } else {
            const int j = i - NW0 - NW1;
            const int e = j & 7, ln = (j >> 3) & 63, ks = (j >> 9) & 1, ct = j >> 10;
            w2tp[j] = f2bf(W2[(ks * 32 + (ln >> 4) * 8 + e) * L2 + ct * 16 + (ln & 15)]);
        }
    }
    if (zrow != nullptr && gid < 128) zrow[gid] = 0u;
    for (int i = gid; i < nfill; i += stride) ssf[i] = NN;
    const int HALF = NN * 32;
    for (int idx = gid; idx < 2 * HALF; idx += stride) {
        const int b = (idx >= HALF) ? 1 : 0;
        const int j = idx - b * HALF;
        const int n = j >> 5;
        const int c4 = j & 31;
        const float4 v = *(const float4*)(x + ((size_t)b * NN + n) * DD + c4 * 4);
        ushort4 o;
        o.x = f2bf(v.x); o.y = f2bf(v.y); o.z = f2bf(v.z); o.w = f2bf(v.w);
        *(ushort4*)(xb + ((size_t)n * 2 + b) * DD + c4 * 4) = o;
    }
    for (int e = gid; e < E; e += stride)
        atomicAdd(&counts[ei[(size_t)E + e]], 1);
}

// ---------------- K2: fused two-level scan (8-padded degrees) ----------------
// 49 blocks x 1024. Chunk-local exclusive offsets + blksum; the LAST-arriving
// block (49-block done-counter — safe sync regime) scans the 49 chunk sums
// into blkoff[] + grand total. Downstream kernels add blkoff[d>>10].
__global__ __launch_bounds__(1024) void k_scanA(
    const int* __restrict__ counts, int* __restrict__ offsets,
    int* __restrict__ blksum, int* __restrict__ blkoff,
    int* __restrict__ wtotb, int* __restrict__ scnt, int n, int nblk)
{
    __shared__ int wsum[16], woff[16];
    __shared__ int lastf;
    const int tid = threadIdx.x, lane = tid & 63, wv = tid >> 6;
    const int i = blockIdx.x * 1024 + tid;
    int v = (i < n) ? ((counts[i] + 7) & ~7) : 0;
    int x = v;
    #pragma unroll
    for (int d = 1; d < 64; d <<= 1) { int t = __shfl_up(x, d); if (lane >= d) x += t; }
    if (lane == 63) wsum[wv] = x;
    __syncthreads();
    if (wv == 0 && lane < 16) {
        int y = wsum[lane];
        #pragma unroll
        for (int d = 1; d < 16; d <<= 1) { int t = __shfl_up(y, d); if (lane >= d) y += t; }
        woff[lane] = y - wsum[lane];
        if (lane == 15) blksum[blockIdx.x] = y;
    }
    __syncthreads();
    if (i < n) offsets[i] = woff[wv] + (x - v);

    // non-blocking last-block chunk-sum scan (49 blocks only)
    __threadfence();                       // release blksum write
    __syncthreads();
    if (tid == 0)
        lastf = (atomicAdd(scnt, 1) == nblk - 1) ? 1 : 0;
    __syncthreads();
    if (lastf && wv == 0) {
        int s = (lane < nblk) ? atomicAdd(&blksum[lane], 0) : 0;   // coherent read
        int xx = s;
        #pragma unroll
        for (int d = 1; d < 64; d <<= 1) { int t = __shfl_up(xx, d); if (lane >= d) xx += t; }
        if (lane < nblk) blkoff[lane] = xx - s;        // exclusive
        if (lane == nblk - 1) wtotb[0] = xx;           // grand total
    }
}

// ---------------- K3: CSR build: bucket src indices by dst ----------------
__global__ __launch_bounds__(256) void k_bucket(
    const int* __restrict__ ei, const int* __restrict__ offsets,
    const int* __restrict__ blkoff, int* __restrict__ cursor,
    int* __restrict__ ss, int E)
{
    int e = blockIdx.x * 256 + threadIdx.x;
    if (e < E) {
        int d = ei[E + e];
        int pos = offsets[d] + blkoff[d >> 10] + atomicAdd(&cursor[d], 1);
        ss[pos] = ei[e];
    }
}

// ---------------- K4: fused gather-agg + (agg@W) + gelu + MLP + colsums ------
// Block: 16 nodes (32 storage rows), 256 threads (4 waves). NO device-scope
// sync in this wide kernel (r11 lesson: per-block fence+contended RMW across
// 3125 blocks cost ~460 µs). Partials written; 64-block k_reduce_final follows.
template<bool FUSED>
__global__ __launch_bounds__(256, 8) void k_mlp_t(
    const unsigned short* __restrict__ src,   // FUSED ? xb : aggb
    const int* __restrict__ offsets, const int* __restrict__ ss,
    const int* __restrict__ blkoff, const int* __restrict__ wtotb,
    const unsigned short* __restrict__ wtp, const float* __restrict__ b0v,
    const unsigned short* __restrict__ w1tp, const float* __restrict__ b1v,
    const unsigned short* __restrict__ w2tp, const float* __restrict__ b2v,
    float* __restrict__ partials, int srows)
{
    __shared__ __align__(16) unsigned char upool[32 * 136 * 2]; // xa/hsb/h2p
    __shared__ __align__(16) unsigned short h1b[32 * 72];       // 4.6 KB
    __shared__ float b0s[DD], b1s[L1], b2s[L2];
    __shared__ float oacc[64];
    unsigned short* xa  = (unsigned short*)upool;   // [32][136] bf16 agg tile
    unsigned short* hsb = (unsigned short*)upool;   // [32][136] bf16 (after xa dead)
    float* h2p = (float*)upool;                     // [32][36] f32 (after hsb dead)

    const int tid = threadIdx.x;
    const int row0 = blockIdx.x * 32;
    const int lane = tid & 63;
    const int w = tid >> 6;       // 0..3

    if (tid < DD) b0s[tid] = b0v[tid];
    if (tid < L1) b1s[tid] = b1v[tid];
    if (tid < L2) b2s[tid] = b2v[tid];
    if (tid < 64) oacc[tid] = 0.f;

    if (FUSED) {
        const int half4 = (lane >> 5) * 4;         // 0 | 4
        const int co = (lane & 31) * 8;            // shorts offset in 512B row
        const int wtot = wtotb[0];
        #pragma unroll
        for (int j = 0; j < 4; ++j) {
            const int ln = w * 4 + j;              // block-local node 0..15
            const int d = blockIdx.x * 16 + ln;    // global node
            int s0 = 0, s1 = 0;
            if (d < NN) {
                s0 = offsets[d] + blkoff[d >> 10];
                s1 = (d + 1 < NN) ? offsets[d + 1] + blkoff[(d + 1) >> 10] : wtot;
            }
            float a[8];
            #pragma unroll
            for (int t = 0; t < 8; ++t) a[t] = 0.f;
            uint4 nidx;
            if (s0 < s1) nidx = *(const uint4*)(ss + s0 + half4);
            for (int i = s0; i < s1; ) {
                const uint4 idx = nidx;
                const int inext = i + 8;
                if (inext < s1) nidx = *(const uint4*)(ss + inext + half4);
                const uint4 r0 = *(const uint4*)(src + (size_t)idx.x * 256 + co);
                const uint4 r1 = *(const uint4*)(src + (size_t)idx.y * 256 + co);
                const uint4 r2 = *(const uint4*)(src + (size_t)idx.z * 256 + co);
                const uint4 r3 = *(const uint4*)(src + (size_t)idx.w * 256 + co);
                a[0] += bf2f_lo(r0.x); a[1] += bf2f_hi(r0.x);
                a[2] += bf2f_lo(r0.y); a[3] += bf2f_hi(r0.y);
                a[4] += bf2f_lo(r0.z); a[5] += bf2f_hi(r0.z);
                a[6] += bf2f_lo(r0.w); a[7] += bf2f_hi(r0.w);
                a[0] += bf2f_lo(r1.x); a[1] += bf2f_hi(r1.x);
                a[2] += bf2f_lo(r1.y); a[3] += bf2f_hi(r1.y);
                a[4] += bf2f_lo(r1.z); a[5] += bf2f_hi(r1.z);
                a[6] += bf2f_lo(r1.w); a[7] += bf2f_hi(r1.w);
                a[0] += bf2f_lo(r2.x); a[1] += bf2f_hi(r2.x);
                a[2] += bf2f_lo(r2.y); a[3] += bf2f_hi(r2.y);
                a[4] += bf2f_lo(r2.z); a[5] += bf2f_hi(r2.z);
                a[6] += bf2f_lo(r2.w); a[7] += bf2f_hi(r2.w);
                a[0] += bf2f_lo(r3.x); a[1] += bf2f_hi(r3.x);
                a[2] += bf2f_lo(r3.y); a[3] += bf2f_hi(r3.y);
                a[4] += bf2f_lo(r3.z); a[5] += bf2f_hi(r3.z);
                a[6] += bf2f_lo(r3.w); a[7] += bf2f_hi(r3.w);
                i = inext;
            }
            #pragma unroll
            for (int t = 0; t < 8; ++t) a[t] += __shfl_xor(a[t], 32);
            if (lane < 32) {
                const int tr = ln * 2 + (lane >> 4);   // storage row in tile
                const int col = (lane & 15) * 8;
                uint4 o;
                o.x = pack2(a[0], a[1]); o.y = pack2(a[2], a[3]);
                o.z = pack2(a[4], a[5]); o.w = pack2(a[6], a[7]);
                *(uint4*)(&xa[tr * 136 + col]) = o;
            }
        }
    } else {
        for (int u = tid * 8; u < 32 * DD; u += 2048) {
            const int r = u >> 7, c = u & 127;
            uint4 raw = make_uint4(0, 0, 0, 0);
            if (row0 + r < srows) raw = *(const uint4*)(src + (size_t)(row0 + r) * HH + c);
            *(uint4*)(&xa[r * 136 + c]) = raw;
        }
    }
    __syncthreads();

    const int lm = lane & 15;
    const int q = lane >> 4;
    const int r1 = (w & 1) * 16;  // row-tile base (0/16)
    const int ch = w >> 1;        // column half 0/1

    // W-GEMM (32x128 @ 128x128)
    {
        v4f acc[4];
        #pragma unroll
        for (int i = 0; i < 4; ++i) acc[i] = (v4f)(0.f);
        #pragma unroll
        for (int ks = 0; ks < 4; ++ks) {
            const int k0 = ks * 32 + q * 8;
            const v8s af = *(const v8s*)(&xa[(r1 + lm) * 136 + k0]);
            #pragma unroll
            for (int ct = 0; ct < 4; ++ct) {
                const int ctg = ch * 4 + ct;
                const v8s bf = *(const v8s*)(wtp + ((size_t)(ctg * 4 + ks) * 64 + lane) * 8);
                acc[ct] = __builtin_amdgcn_mfma_f32_16x16x32_bf16(af, bf, acc[ct], 0, 0, 0);
            }
        }
        __syncthreads();   // xa reads done; upool becomes hsb
        #pragma unroll
        for (int ct = 0; ct < 4; ++ct) {
            const int col = ch * 64 + ct * 16 + lm;
            const float bias = b0s[col];
            #pragma unroll
            for (int r = 0; r < 4; ++r)
                hsb[(r1 + q * 4 + r) * 136 + col] = f2bf(gelu_f(acc[ct][r] + bias));
        }
    }
    __syncthreads();

    // layer1 (32x128 @ 128x64)
    {
        v4f a1[2];
        a1[0] = (v4f)(0.f); a1[1] = (v4f)(0.f);
        #pragma unroll
        for (int ks = 0; ks < 4; ++ks) {
            const int k0 = ks * 32 + q * 8;
            const v8s af = *(const v8s*)(&hsb[(r1 + lm) * 136 + k0]);
            #pragma unroll
            for (int ct = 0; ct < 2; ++ct) {
                const int ctg = ch * 2 + ct;
                const v8s bf = *(const v8s*)(w1tp + ((size_t)(ctg * 4 + ks) * 64 + lane) * 8);
                a1[ct] = __builtin_amdgcn_mfma_f32_16x16x32_bf16(af, bf, a1[ct], 0, 0, 0);
            }
        }
        #pragma unroll
        for (int ct = 0; ct < 2; ++ct) {
            const int col = ch * 32 + ct * 16 + lm;
            const float bias = b1s[col];
            #pragma unroll
            for (int r = 0; r < 4; ++r)
                h1b[(r1 + q * 4 + r) * 72 + col] = f2bf(fmaxf(a1[ct][r] + bias, 0.f));
        }
    }
    __syncthreads();

    // layer2 (32x64 @ 64x32)
    {
        v4f a2 = (v4f)(0.f);
        #pragma unroll
        for (int ks = 0; ks < 2; ++ks) {
            const int k0 = ks * 32 + q * 8;
            const v8s af = *(const v8s*)(&h1b[(r1 + lm) * 72 + k0]);
            const v8s bf = *(const v8s*)(w2tp + ((size_t)(ch * 2 + ks) * 64 + lane) * 8);
            a2 = __builtin_amdgcn_mfma_f32_16x16x32_bf16(af, bf, a2, 0, 0, 0);
        }
        __syncthreads();   // hsb (upool) reads done; reuse as h2p
        const int col = ch * 16 + lm;
        const float bias = b2s[col];
        #pragma unroll
        for (int r = 0; r < 4; ++r)
            h2p[(r1 + q * 4 + r) * 36 + col] = fmaxf(a2[r] + bias, 0.f);
    }
    __syncthreads();

    // column sums: storage row r -> batch r&1
    {
        const int c = tid & 31;
        const int g = tid >> 5;   // 0..7, 4 rows each
        float p0 = 0.f, p1 = 0.f;
        #pragma unroll
        for (int i = 0; i < 4; ++i) {
            const int r = g * 4 + i;
            if (row0 + r < srows) {
                const float v = h2p[r * 36 + c];
                if (r & 1) p1 += v; else p0 += v;
            }
        }
        if (p0 != 0.f) atomicAdd(&oacc[c], p0);
        if (p1 != 0.f) atomicAdd(&oacc[32 + c], p1);
    }
    __syncthreads();
    if (tid < 64) partials[(size_t)blockIdx.x * 64 + tid] = oacc[tid];
}

// ---------------- Fallback path (ws too small for CSR) ----------------
__global__ __launch_bounds__(256) void k_scatter(
    const int* __restrict__ ei, const unsigned short* __restrict__ xb,
    float* __restrict__ aggf, int E)
{
    const int tid = threadIdx.x;
    const int eg = tid >> 6;
    const int lane = tid & 63;
    const int e = blockIdx.x * 4 + eg;
    if (e >= E) return;
    const int src = ei[e];
    const int dst = ei[E + e];
    const uint2 r = *(const uint2*)(xb + (size_t)src * 256 + lane * 4);
    float* ap = aggf + (size_t)dst * 256 + lane * 4;
    unsafeAtomicAdd(ap + 0, bf2f_lo(r.x));
    unsafeAtomicAdd(ap + 1, bf2f_hi(r.x));
    unsafeAtomicAdd(ap + 2, bf2f_lo(r.y));
    unsafeAtomicAdd(ap + 3, bf2f_hi(r.y));
}

__global__ __launch_bounds__(256) void k_cvt(
    const float* __restrict__ in, unsigned short* __restrict__ outb, int n)
{
    int i = blockIdx.x * 256 + threadIdx.x;
    if (i < n) outb[i] = f2bf(in[i]);
}

// ---------------- K5: reduce partials + last-block applies layer3 ------------
// 64 blocks: safe sync regime for the done-counter pattern (r2-r6 proven).
__global__ __launch_bounds__(256) void k_reduce_final(
    const float* __restrict__ partials, float* __restrict__ accum, int nblk,
    int* __restrict__ dcnt, const float* __restrict__ W3,
    const float* __restrict__ b3v, float* __restrict__ out)
{
    __shared__ float lsum[4][64];
    __shared__ int lastf;
    const int t = threadIdx.x & 63;
    const int w = threadIdx.x >> 6;
    float s = 0.f;
    for (int g = blockIdx.x * 4 + w; g < nblk; g += gridDim.x * 4)
        s += partials[(size_t)g * 64 + t];
    lsum[w][t] = s;
    __syncthreads();
    if (threadIdx.x < 64) {
        const float v = lsum[0][t] + lsum[1][t] + lsum[2][t] + lsum[3][t];
        unsafeAtomicAdd(&accum[t], v);
    }
    __threadfence();                      // release: accum atomics visible
    __syncthreads();
    if (threadIdx.x == 0)
        lastf = (atomicAdd(dcnt, 1) == (int)gridDim.x - 1) ? 1 : 0;
    __syncthreads();
    if (lastf && threadIdx.x < 2 * OO) {
        const int b = threadIdx.x / OO, o = threadIdx.x % OO;
        float acc = b3v[o];
        const float inv = 1.0f / (float)NN;
        #pragma unroll
        for (int j = 0; j < L2; ++j)
            acc += (unsafeAtomicAdd(&accum[b * 32 + j], 0.f) * inv) * W3[j * OO + o];
        out[threadIdx.x] = acc;
    }
}

extern "C" void kernel_launch(void* const* d_in, const int* in_sizes, int n_in,
                              void* d_out, int out_size, void* d_ws, size_t ws_size,
                              hipStream_t stream) {
    const float* x  = (const float*)d_in[0];
    const int*   ei = (const int*)d_in[1];
    const float* W  = (const float*)d_in[2];
    const float* b0 = (const float*)d_in[3];
    const float* W1 = (const float*)d_in[4];
    const float* b1 = (const float*)d_in[5];
    const float* W2 = (const float*)d_in[6];
    const float* b2 = (const float*)d_in[7];
    const float* W3 = (const float*)d_in[8];
    const float* b3 = (const float*)d_in[9];
    float* out = (float*)d_out;

    const int E = in_sizes[1] / 2;           // 800000
    const int rows = 2 * NN;                 // 100000 storage rows
    const int NT = (rows + 31) / 32;         // 3125 mlp tiles
    const int nsc = (NN + 1023) / 1024;      // 49 scan chunks
    const int SSN = E + 7 * NN + 8;          // padded CSR capacity

    // ---- CSR-path workspace layout ----
    unsigned short* xb = (unsigned short*)d_ws;                      // rows*HH bf16
    unsigned* zrow     = (unsigned*)(xb + (size_t)rows * HH);        // 512 B zero row
    int*   ss       = (int*)(zrow + 128);                            // SSN
    float* partials = (float*)(ss + SSN);                            // NT*64
    float* accum    = partials + (size_t)NT * 64;                    // 64  <- zero from here
    int*   dcnt     = (int*)(accum + 64);                            // 16
    int*   scnt     = dcnt + 16;                                     // 16
    int*   counts   = scnt + 16;                                     // NN
    int*   cursor   = counts + NN;                                   // NN  <- zero to here
    int*   offsets  = cursor + NN;                                   // NN+1
    int*   blksum   = offsets + NN + 1;                              // 64
    int*   blkoff   = blksum + 64;                                   // 64
    int*   wtotb    = blkoff + 64;                                   // 16
    unsigned short* wtp = (unsigned short*)(((uintptr_t)(wtotb + 16) + 15) & ~(uintptr_t)15);
    unsigned short* w1tp = wtp + NW0;
    unsigned short* w2tp = w1tp + NW1;
    const size_t need_csr = (size_t)((char*)(w2tp + NW2) - (char*)d_ws) + 16;
    const size_t zeroN = 96 + 2 * (size_t)NN;   // accum,dcnt,scnt,counts,cursor (ints)

    // ---- fallback workspace layout ----
    unsigned short* g_aggb = xb + (size_t)rows * HH;
    float* g_partials = (float*)(g_aggb + (size_t)rows * HH);
    float* g_accum    = g_partials + (size_t)NT * 64;
    int*   g_dcnt     = (int*)(g_accum + 64);
    unsigned short* g_wtp = (unsigned short*)(((uintptr_t)(g_dcnt + 16) + 15) & ~(uintptr_t)15);
    unsigned short* g_w1tp = g_wtp + NW0;
    unsigned short* g_w2tp = g_w1tp + NW1;
    float* g_aggf     = (float*)(((uintptr_t)(g_w2tp + NW2) + 15) & ~(uintptr_t)15);
    const size_t need_fb = (size_t)((char*)(g_aggf + (size_t)rows * HH) - (char*)d_ws) + 16;

    if (ws_size >= need_csr && nsc <= 49) {
        hipMemsetAsync(accum, 0, zeroN * sizeof(int), stream);
        k_prep<<<dim3(2048), dim3(256), 0, stream>>>(
            x, xb, ei, counts, W, W1, W2, wtp, w1tp, w2tp, ss, SSN, zrow, E);
        k_scanA<<<dim3(nsc), dim3(1024), 0, stream>>>(
            counts, offsets, blksum, blkoff, wtotb, scnt, NN, nsc);
        k_bucket<<<dim3((E + 255) / 256), dim3(256), 0, stream>>>(
            ei, offsets, blkoff, cursor, ss, E);
        k_mlp_t<true><<<dim3(NT), dim3(256), 0, stream>>>(
            xb, offsets, ss, blkoff, wtotb, wtp, b0, w1tp, b1, w2tp, b2,
            partials, rows);
        k_reduce_final<<<dim3(64), dim3(256), 0, stream>>>(
            partials, accum, NT, dcnt, W3, b3, out);
    } else if (ws_size >= need_fb) {
        hipMemsetAsync(g_accum, 0, 80 * sizeof(int), stream);
        hipMemsetAsync(g_aggf, 0, (size_t)rows * HH * sizeof(float), stream);
        k_prep<<<dim3(2048), dim3(256), 0, stream>>>(
            x, xb, ei, g_dcnt /*unused*/, W, W1, W2, g_wtp, g_w1tp, g_w2tp,
            g_dcnt, 0, nullptr, 0);
        k_scatter<<<dim3((E + 3) / 4), dim3(256), 0, stream>>>(ei, xb, g_aggf, E);
        k_cvt<<<dim3((rows * HH + 255) / 256), dim3(256), 0, stream>>>(g_aggf, g_aggb, rows * HH);
        k_mlp_t<false><<<dim3(NT), dim3(256), 0, stream>>>(
            g_aggb, nullptr, nullptr, nullptr, nullptr, g_wtp, b0, g_w1tp, b1,
            g_w2tp, b2, g_partials, rows);
        k_reduce_final<<<dim3(64), dim3(256), 0, stream>>>(
            g_partials, g_accum, NT, g_dcnt, W3, b3, out);
    }
}

// Round 13
// 262.866 us; speedup vs baseline: 4.2748x; 1.1001x over previous
//
#include <hip/hip_runtime.h>
#include <math.h>

#define NN 50000
#define DD 128
#define HH 128
#define L1 64
#define L2 32
#define OO 10

// packed B-fragment table sizes (ct * ks * 64 lanes * 8 elems)
#define NW0 16384   // W : 8 ct * 4 ks * 64 * 8
#define NW1 8192    // W1: 4 ct * 4 ks * 64 * 8
#define NW2 2048    // W2: 2 ct * 2 ks * 64 * 8

typedef short v8s __attribute__((ext_vector_type(8)));   // 8 bf16 (4 VGPRs)
typedef float v4f __attribute__((ext_vector_type(4)));   // MFMA accumulator

// ---- bf16 helpers (manual: RNE pack) ----
__device__ __forceinline__ float bf2f_lo(unsigned u) { return __uint_as_float(u << 16); }
__device__ __forceinline__ float bf2f_hi(unsigned u) { return __uint_as_float(u & 0xffff0000u); }
__device__ __forceinline__ unsigned short f2bf(float f) {
    unsigned u = __float_as_uint(f);
    return (unsigned short)((u + 0x7fffu + ((u >> 16) & 1u)) >> 16);
}
__device__ __forceinline__ unsigned pack2(float lo, float hi) {
    return (unsigned)f2bf(lo) | ((unsigned)f2bf(hi) << 16);
}
__device__ __forceinline__ float gelu_f(float v) {
    return 0.5f * v * (1.f + erff(v * 0.70710678118654752f));
}

// ---------------- K0: pack W, W1, W2 into MFMA B-fragment order ----------------
// frag index: ((ct*KS + ks)*64 + lane)*8 + e ; element = Wx[k][n],
// k = ks*32 + (lane>>4)*8 + e, n = ct*16 + (lane&15).
// A wave's B-load is then 64 lanes x 16B contiguous (1KB coalesced burst).
__global__ __launch_bounds__(256) void k_wprep(
    const float* __restrict__ W, const float* __restrict__ W1,
    const float* __restrict__ W2, unsigned short* __restrict__ wtp,
    unsigned short* __restrict__ w1tp, unsigned short* __restrict__ w2tp)
{
    int i = blockIdx.x * 256 + threadIdx.x;
    if (i < NW0) {
        const int e = i & 7, ln = (i >> 3) & 63, ks = (i >> 9) & 3, ct = i >> 11;
        wtp[i] = f2bf(W[(ks * 32 + (ln >> 4) * 8 + e) * HH + ct * 16 + (ln & 15)]);
    } else if (i < NW0 + NW1) {
        const int j = i - NW0;
        const int e = j & 7, ln = (j >> 3) & 63, ks = (j >> 9) & 3, ct = j >> 11;
        w1tp[j] = f2bf(W1[(ks * 32 + (ln >> 4) * 8 + e) * L1 + ct * 16 + (ln & 15)]);
    } else if (i < NW0 + NW1 + NW2) {
        const int j = i - NW0 - NW1;
        const int e = j & 7, ln = (j >> 3) & 63, ks = (j >> 9) & 1, ct = j >> 10;
        w2tp[j] = f2bf(W2[(ks * 32 + (ln >> 4) * 8 + e) * L2 + ct * 16 + (ln & 15)]);
    }
}

// ---------------- K1: x -> interleaved bf16 + fused dst histogram -------------
__global__ __launch_bounds__(256) void k_xcvt(
    const float* __restrict__ x, unsigned short* __restrict__ xb,
    const int* __restrict__ ei, int* __restrict__ counts, int E)
{
    const int gid = blockIdx.x * 256 + threadIdx.x;
    const int stride = gridDim.x * 256;
    const int HALF = NN * 32;                 // float4-chunks per batch
    for (int idx = gid; idx < 2 * HALF; idx += stride) {
        const int b = (idx >= HALF) ? 1 : 0;
        const int j = idx - b * HALF;
        const int n = j >> 5;
        const int c4 = j & 31;
        const float4 v = *(const float4*)(x + ((size_t)b * NN + n) * DD + c4 * 4);
        ushort4 o;
        o.x = f2bf(v.x); o.y = f2bf(v.y); o.z = f2bf(v.z); o.w = f2bf(v.w);
        *(ushort4*)(xb + ((size_t)n * 2 + b) * DD + c4 * 4) = o;
    }
    for (int e = gid; e < E; e += stride)
        atomicAdd(&counts[ei[(size_t)E + e]], 1);
}

// ---------------- multi-block scan, stage 1 ----------------
__global__ __launch_bounds__(1024) void k_scan1(
    const int* __restrict__ counts, int* __restrict__ offsets,
    int* __restrict__ blksum, int n)
{
    __shared__ int wsum[16], woff[16];
    const int tid = threadIdx.x, lane = tid & 63, wv = tid >> 6;
    const int i = blockIdx.x * 1024 + tid;
    int v = (i < n) ? counts[i] : 0;
    int x = v;
    #pragma unroll
    for (int d = 1; d < 64; d <<= 1) { int t = __shfl_up(x, d); if (lane >= d) x += t; }
    if (lane == 63) wsum[wv] = x;
    __syncthreads();
    if (wv == 0 && lane < 16) {
        int y = wsum[lane];
        #pragma unroll
        for (int d = 1; d < 16; d <<= 1) { int t = __shfl_up(y, d); if (lane >= d) y += t; }
        woff[lane] = y - wsum[lane];
        if (lane == 15) blksum[blockIdx.x] = y;
    }
    __syncthreads();
    if (i < n) offsets[i] = woff[wv] + (x - v);
}

// ---------------- multi-block scan, stage 2 ----------------
__global__ __launch_bounds__(1024) void k_scan2(
    int* __restrict__ offsets, const int* __restrict__ blksum, int nblk, int n)
{
    __shared__ int base_sh, tot_sh;
    const int tid = threadIdx.x, lane = tid & 63, wv = tid >> 6;
    if (wv == 0) {
        int v = (lane < nblk) ? blksum[lane] : 0;
        int x = v;
        #pragma unroll
        for (int d = 1; d < 64; d <<= 1) { int t = __shfl_up(x, d); if (lane >= d) x += t; }
        int incl = __shfl(x, blockIdx.x);
        int own  = __shfl(v, blockIdx.x);
        int tot  = __shfl(x, nblk - 1);
        if (lane == 0) { base_sh = incl - own; tot_sh = tot; }
    }
    __syncthreads();
    const int i = blockIdx.x * 1024 + tid;
    if (i < n) offsets[i] += base_sh;
    if (blockIdx.x == nblk - 1 && tid == 0) offsets[n] = tot_sh;
}

// ---------------- CSR build: bucket src indices by dst ----------------
__global__ __launch_bounds__(256) void k_bucket(
    const int* __restrict__ ei, const int* __restrict__ offsets,
    int* __restrict__ cursor, int* __restrict__ ss, int E)
{
    int e = blockIdx.x * 256 + threadIdx.x;
    if (e < E) {
        int d = ei[E + e];
        int pos = offsets[d] + atomicAdd(&cursor[d], 1);
        ss[pos] = ei[e];
    }
}

// ---------------- K3: fused gather-agg + (agg @ W) + gelu + MLP + colsums ----
// Block: 32 nodes (64 storage rows), 512 threads (8 waves).
// FUSED: wave w aggregates nodes w*4..w*4+3 via CSR directly into LDS xa
//   (uint4 16B/lane: lanes 0-31 = even edges, 32-63 = odd edges, shfl_xor(32)
//    combine). All weight B-fragments come from packed global tables
//   (coalesced 1KB bursts, L1-resident); LDS ~28 KB.
template<bool FUSED>
__global__ __launch_bounds__(512, 6) void k_mlp_t(
    const unsigned short* __restrict__ src,   // FUSED ? xb : aggb
    const int* __restrict__ offsets, const int* __restrict__ ss,
    const unsigned short* __restrict__ wtp, const float* __restrict__ b0v,
    const unsigned short* __restrict__ w1tp, const float* __restrict__ b1v,
    const unsigned short* __restrict__ w2tp, const float* __restrict__ b2v,
    float* __restrict__ partials, int srows)
{
    __shared__ __align__(16) unsigned char upool[64 * 136 * 2]; // xa/hsb/h2p
    __shared__ __align__(16) unsigned short h1b[64 * 72];       // 9.2 KB
    __shared__ float b0s[DD], b1s[L1], b2s[L2];
    __shared__ float oacc[64];
    unsigned short* xa  = (unsigned short*)upool;   // [64][136] bf16 agg tile
    unsigned short* hsb = (unsigned short*)upool;   // [64][136] bf16 (after xa dead)
    float* h2p = (float*)upool;                     // [64][36] f32 (after hsb dead)

    const int tid = threadIdx.x;
    const int row0 = blockIdx.x * 64;
    const int lane = tid & 63;
    const int w = tid >> 6;       // 0..7

    if (tid < DD) b0s[tid] = b0v[tid];
    if (tid < L1) b1s[tid] = b1v[tid];
    if (tid < L2) b2s[tid] = b2v[tid];
    if (tid < 64) oacc[tid] = 0.f;

    if (FUSED) {
        // gather-aggregate: wave w handles 4 nodes
        const int sel = (lane < 32) ? 0 : 1;
        const int co = (lane & 31) * 8;            // shorts offset in 512B row
        #pragma unroll
        for (int j = 0; j < 4; ++j) {
            const int ln = w * 4 + j;              // block-local node 0..31
            const int d = blockIdx.x * 32 + ln;    // global node
            const int s0 = (d < NN) ? offsets[d] : 0;
            const int s1 = (d < NN) ? offsets[d + 1] : 0;
            float a[8];
            #pragma unroll
            for (int t = 0; t < 8; ++t) a[t] = 0.f;
            int i = s0;
            for (; i + 4 <= s1; i += 4) {
                const int sA = ss[i + sel];
                const int sB = ss[i + 2 + sel];
                const uint4 ra = *(const uint4*)(src + (size_t)sA * 256 + co);
                const uint4 rb = *(const uint4*)(src + (size_t)sB * 256 + co);
                a[0] += bf2f_lo(ra.x); a[1] += bf2f_hi(ra.x);
                a[2] += bf2f_lo(ra.y); a[3] += bf2f_hi(ra.y);
                a[4] += bf2f_lo(ra.z); a[5] += bf2f_hi(ra.z);
                a[6] += bf2f_lo(ra.w); a[7] += bf2f_hi(ra.w);
                a[0] += bf2f_lo(rb.x); a[1] += bf2f_hi(rb.x);
                a[2] += bf2f_lo(rb.y); a[3] += bf2f_hi(rb.y);
                a[4] += bf2f_lo(rb.z); a[5] += bf2f_hi(rb.z);
                a[6] += bf2f_lo(rb.w); a[7] += bf2f_hi(rb.w);
            }
            if (i + 2 <= s1) {
                const int sA = ss[i + sel];
                const uint4 ra = *(const uint4*)(src + (size_t)sA * 256 + co);
                a[0] += bf2f_lo(ra.x); a[1] += bf2f_hi(ra.x);
                a[2] += bf2f_lo(ra.y); a[3] += bf2f_hi(ra.y);
                a[4] += bf2f_lo(ra.z); a[5] += bf2f_hi(ra.z);
                a[6] += bf2f_lo(ra.w); a[7] += bf2f_hi(ra.w);
                i += 2;
            }
            if (i < s1 && lane < 32) {
                const int sA = ss[i];
                const uint4 ra = *(const uint4*)(src + (size_t)sA * 256 + co);
                a[0] += bf2f_lo(ra.x); a[1] += bf2f_hi(ra.x);
                a[2] += bf2f_lo(ra.y); a[3] += bf2f_hi(ra.y);
                a[4] += bf2f_lo(ra.z); a[5] += bf2f_hi(ra.z);
                a[6] += bf2f_lo(ra.w); a[7] += bf2f_hi(ra.w);
            }
            #pragma unroll
            for (int t = 0; t < 8; ++t) a[t] += __shfl_xor(a[t], 32);
            if (lane < 32) {
                const int tr = ln * 2 + (lane >> 4);   // storage row in tile
                const int col = (lane & 15) * 8;
                uint4 o;
                o.x = pack2(a[0], a[1]); o.y = pack2(a[2], a[3]);
                o.z = pack2(a[4], a[5]); o.w = pack2(a[6], a[7]);
                *(uint4*)(&xa[tr * 136 + col]) = o;
            }
        }
    } else {
        // stage pre-aggregated tile (fallback path)
        for (int u = tid * 8; u < 64 * DD; u += 4096) {
            const int r = u >> 7, c = u & 127;
            uint4 raw = make_uint4(0, 0, 0, 0);
            if (row0 + r < srows) raw = *(const uint4*)(src + (size_t)(row0 + r) * HH + c);
            *(uint4*)(&xa[r * 136 + c]) = raw;
        }
    }
    __syncthreads();

    const int lm = lane & 15;
    const int q = lane >> 4;
    const int r1 = (w & 3) * 16;  // row-tile base
    const int ch = w >> 2;        // column half 0/1

    // W-GEMM (64x128 @ 128x128): wave w -> rows r1..+16, cols ch*64..+64
    {
        v4f acc[4];
        #pragma unroll
        for (int i = 0; i < 4; ++i) acc[i] = (v4f)(0.f);
        #pragma unroll
        for (int ks = 0; ks < 4; ++ks) {
            const int k0 = ks * 32 + q * 8;
            const v8s af = *(const v8s*)(&xa[(r1 + lm) * 136 + k0]);
            #pragma unroll
            for (int ct = 0; ct < 4; ++ct) {
                const int ctg = ch * 4 + ct;
                const v8s bf = *(const v8s*)(wtp + ((size_t)(ctg * 4 + ks) * 64 + lane) * 8);
                acc[ct] = __builtin_amdgcn_mfma_f32_16x16x32_bf16(af, bf, acc[ct], 0, 0, 0);
            }
        }
        __syncthreads();   // all xa reads done; upool becomes hsb

        // bias + gelu -> hsb (A-operand layout for layer1)
        #pragma unroll
        for (int ct = 0; ct < 4; ++ct) {
            const int col = ch * 64 + ct * 16 + lm;
            const float bias = b0s[col];
            #pragma unroll
            for (int r = 0; r < 4; ++r)
                hsb[(r1 + q * 4 + r) * 136 + col] = f2bf(gelu_f(acc[ct][r] + bias));
        }
    }
    __syncthreads();

    // layer1 (64x128 @ 128x64): wave w -> rows r1..+16, cols ch*32..+32
    {
        v4f a1[2];
        a1[0] = (v4f)(0.f); a1[1] = (v4f)(0.f);
        #pragma unroll
        for (int ks = 0; ks < 4; ++ks) {
            const int k0 = ks * 32 + q * 8;
            const v8s af = *(const v8s*)(&hsb[(r1 + lm) * 136 + k0]);
            #pragma unroll
            for (int ct = 0; ct < 2; ++ct) {
                const int ctg = ch * 2 + ct;
                const v8s bf = *(const v8s*)(w1tp + ((size_t)(ctg * 4 + ks) * 64 + lane) * 8);
                a1[ct] = __builtin_amdgcn_mfma_f32_16x16x32_bf16(af, bf, a1[ct], 0, 0, 0);
            }
        }
        #pragma unroll
        for (int ct = 0; ct < 2; ++ct) {
            const int col = ch * 32 + ct * 16 + lm;
            const float bias = b1s[col];
            #pragma unroll
            for (int r = 0; r < 4; ++r)
                h1b[(r1 + q * 4 + r) * 72 + col] = f2bf(fmaxf(a1[ct][r] + bias, 0.f));
        }
    }
    __syncthreads();

    // layer2 (64x64 @ 64x32): wave w -> rows r1..+16, cols ch*16..+16
    {
        v4f a2 = (v4f)(0.f);
        #pragma unroll
        for (int ks = 0; ks < 2; ++ks) {
            const int k0 = ks * 32 + q * 8;
            const v8s af = *(const v8s*)(&h1b[(r1 + lm) * 72 + k0]);
            const v8s bf = *(const v8s*)(w2tp + ((size_t)(ch * 2 + ks) * 64 + lane) * 8);
            a2 = __builtin_amdgcn_mfma_f32_16x16x32_bf16(af, bf, a2, 0, 0, 0);
        }
        __syncthreads();   // hsb (upool) reads long done; reuse as h2p
        const int col = ch * 16 + lm;
        const float bias = b2s[col];
        #pragma unroll
        for (int r = 0; r < 4; ++r)
            h2p[(r1 + q * 4 + r) * 36 + col] = fmaxf(a2[r] + bias, 0.f);
    }
    __syncthreads();

    // column sums: storage row r -> batch r&1
    {
        const int c = tid & 31;
        const int g = tid >> 5;   // 0..15, 4 rows each
        float p0 = 0.f, p1 = 0.f;
        #pragma unroll
        for (int i = 0; i < 4; ++i) {
            const int r = g * 4 + i;
            if (row0 + r < srows) {
                const float v = h2p[r * 36 + c];
                if (r & 1) p1 += v; else p0 += v;
            }
        }
        if (p0 != 0.f) atomicAdd(&oacc[c], p0);
        if (p1 != 0.f) atomicAdd(&oacc[32 + c], p1);
    }
    __syncthreads();
    if (tid < 64) partials[(size_t)blockIdx.x * 64 + tid] = oacc[tid];
}

// ---------------- Fallback path (ws too small for CSR) ----------------
__global__ __launch_bounds__(256) void k_scatter(
    const int* __restrict__ ei, const unsigned short* __restrict__ xb,
    float* __restrict__ aggf, int E)
{
    const int tid = threadIdx.x;
    const int eg = tid >> 6;
    const int lane = tid & 63;
    const int e = blockIdx.x * 4 + eg;
    if (e >= E) return;
    const int src = ei[e];
    const int dst = ei[E + e];
    const uint2 r = *(const uint2*)(xb + (size_t)src * 256 + lane * 4);
    float* ap = aggf + (size_t)dst * 256 + lane * 4;
    unsafeAtomicAdd(ap + 0, bf2f_lo(r.x));
    unsafeAtomicAdd(ap + 1, bf2f_hi(r.x));
    unsafeAtomicAdd(ap + 2, bf2f_lo(r.y));
    unsafeAtomicAdd(ap + 3, bf2f_hi(r.y));
}

__global__ __launch_bounds__(256) void k_cvt(
    const float* __restrict__ in, unsigned short* __restrict__ outb, int n)
{
    int i = blockIdx.x * 256 + threadIdx.x;
    if (i < n) outb[i] = f2bf(in[i]);
}

// ---------------- K4a: parallel reduce of partials ----------------
__global__ __launch_bounds__(256) void k_reduce(
    const float* __restrict__ partials, float* __restrict__ accum, int nblk)
{
    __shared__ float lsum[4][64];
    const int t = threadIdx.x & 63;
    const int w = threadIdx.x >> 6;
    float s = 0.f;
    for (int g = blockIdx.x * 4 + w; g < nblk; g += gridDim.x * 4)
        s += partials[(size_t)g * 64 + t];
    lsum[w][t] = s;
    __syncthreads();
    if (threadIdx.x < 64) {
        const float v = lsum[0][t] + lsum[1][t] + lsum[2][t] + lsum[3][t];
        unsafeAtomicAdd(&accum[t], v);
    }
}

// ---------------- K4b: apply layer3 to mean(h2) ----------------
__global__ __launch_bounds__(64) void k_final(
    const float* __restrict__ accum, const float* __restrict__ W3,
    const float* __restrict__ b3v, float* __restrict__ out)
{
    const int tid = threadIdx.x;
    if (tid < 2 * OO) {
        const int b = tid / OO, o = tid % OO;
        float acc = b3v[o];
        const float inv = 1.0f / (float)NN;
        #pragma unroll
        for (int j = 0; j < L2; ++j) acc += (accum[b * 32 + j] * inv) * W3[j * OO + o];
        out[tid] = acc;
    }
}

extern "C" void kernel_launch(void* const* d_in, const int* in_sizes, int n_in,
                              void* d_out, int out_size, void* d_ws, size_t ws_size,
                              hipStream_t stream) {
    const float* x  = (const float*)d_in[0];
    const int*   ei = (const int*)d_in[1];
    const float* W  = (const float*)d_in[2];
    const float* b0 = (const float*)d_in[3];
    const float* W1 = (const float*)d_in[4];
    const float* b1 = (const float*)d_in[5];
    const float* W2 = (const float*)d_in[6];
    const float* b2 = (const float*)d_in[7];
    const float* W3 = (const float*)d_in[8];
    const float* b3 = (const float*)d_in[9];
    float* out = (float*)d_out;

    const int E = in_sizes[1] / 2;           // 800000
    const int rows = 2 * NN;                 // 100000 storage rows
    const int nblk = (rows + 63) / 64;       // 1563 (mlp blocks, 32 nodes each)
    const int nsb = (NN + 1023) / 1024;      // 49 scan blocks
    const int wpn = NW0 + NW1 + NW2;         // 26624 packed weight elements

    // workspace layout
    unsigned short* xb   = (unsigned short*)d_ws;                    // rows*HH bf16 (interleaved x)
    unsigned short* aggb = xb + (size_t)rows * HH;                   // rows*HH bf16 (fallback only)
    float* partials = (float*)(aggb + (size_t)rows * HH);            // nblk*64
    float* accum    = partials + (size_t)nblk * 64;                  // 64
    int*   counts   = (int*)(accum + 64);                            // NN
    int*   cursor   = counts + NN;                                   // NN
    int*   offsets  = cursor + NN;                                   // NN+1
    int*   blksum   = offsets + NN + 1;                              // 64
    unsigned short* wtp = (unsigned short*)(((uintptr_t)(blksum + 64) + 15) & ~(uintptr_t)15);
    unsigned short* w1tp = wtp + NW0;
    unsigned short* w2tp = w1tp + NW1;
    int*   ss       = (int*)(w2tp + NW2);                            // E
    float* aggf     = (float*)(ss + E);                              // rows*HH (fallback only)
    const size_t need_csr = ((size_t)rows * HH * 2 + wpn) * sizeof(unsigned short)
                      + ((size_t)nblk * 64 + 64) * sizeof(float)
                      + ((size_t)NN * 3 + 1 + 64 + E) * sizeof(int) + 16;
    const size_t need_fb = need_csr + (size_t)rows * HH * sizeof(float);

    if (ws_size >= need_csr && nsb <= 64) {
        hipMemsetAsync(accum, 0, (64 + 2 * (size_t)NN) * sizeof(int), stream);
        k_wprep<<<dim3((wpn + 255) / 256), dim3(256), 0, stream>>>(W, W1, W2, wtp, w1tp, w2tp);
        k_xcvt<<<dim3(2048), dim3(256), 0, stream>>>(x, xb, ei, counts, E);
        k_scan1<<<dim3(nsb), dim3(1024), 0, stream>>>(counts, offsets, blksum, NN);
        k_scan2<<<dim3(nsb), dim3(1024), 0, stream>>>(offsets, blksum, nsb, NN);
        k_bucket<<<dim3((E + 255) / 256), dim3(256), 0, stream>>>(ei, offsets, cursor, ss, E);
        k_mlp_t<true><<<dim3(nblk), dim3(512), 0, stream>>>(
            xb, offsets, ss, wtp, b0, w1tp, b1, w2tp, b2, partials, rows);
    } else if (ws_size >= need_fb) {
        hipMemsetAsync(accum, 0, 64 * sizeof(float), stream);
        hipMemsetAsync(aggf, 0, (size_t)rows * HH * sizeof(float), stream);
        k_wprep<<<dim3((wpn + 255) / 256), dim3(256), 0, stream>>>(W, W1, W2, wtp, w1tp, w2tp);
        k_xcvt<<<dim3(2048), dim3(256), 0, stream>>>(x, xb, ei, counts, 0);
        k_scatter<<<dim3((E + 3) / 4), dim3(256), 0, stream>>>(ei, xb, aggf, E);
        k_cvt<<<dim3((rows * HH + 255) / 256), dim3(256), 0, stream>>>(aggf, aggb, rows * HH);
        k_mlp_t<false><<<dim3(nblk), dim3(512), 0, stream>>>(
            aggb, offsets, ss, wtp, b0, w1tp, b1, w2tp, b2, partials, rows);
    }

    k_reduce<<<dim3(64), dim3(256), 0, stream>>>(partials, accum, nblk);
    k_final<<<dim3(1), dim3(64), 0, stream>>>(accum, W3, b3, out);
}